// Round 7
// baseline (438.620 us; speedup 1.0000x reference)
//
#include <hip/hip_runtime.h>
#include <hip/hip_bf16.h>
#include <hip/hip_cooperative_groups.h>

typedef unsigned short ushort_t;
typedef __attribute__((ext_vector_type(4))) float floatx4;
typedef __attribute__((ext_vector_type(8))) short short8;

#define L2E 1.4426950408889634f

__device__ __forceinline__ float bf2f(ushort_t u) {
    union { unsigned int i; float f; } v; v.i = ((unsigned int)u) << 16; return v.f;
}
__device__ __forceinline__ ushort_t f2bf(float f) {
    union { float f; unsigned int i; } v; v.f = f;
    unsigned int i = v.i;
    i += 0x7fffu + ((i >> 16) & 1u);            // RNE
    return (ushort_t)(i >> 16);
}
__device__ __forceinline__ float fexp2(float x) {
#if __has_builtin(__builtin_amdgcn_exp2f)
    return __builtin_amdgcn_exp2f(x);
#else
    return __expf(x * 0.6931471805599453f);
#endif
}
__device__ __forceinline__ float frcp(float x) {
#if __has_builtin(__builtin_amdgcn_rcpf)
    return __builtin_amdgcn_rcpf(x);
#else
    return 1.f / x;
#endif
}
// σ(x) with pre-scaled input a = −log2e·x ; tanh(x) with y = 2·log2e·x.
__device__ __forceinline__ float sig2(float a)  { return frcp(1.f + fexp2(a)); }
__device__ __forceinline__ float tanh2(float y) { return 1.f - 2.f * frcp(1.f + fexp2(y)); }

__device__ __forceinline__ unsigned int packbf(float a, float b) {
    float2 t; t.x = a; t.y = b;
    __hip_bfloat162 h = __float22bfloat162_rn(t);
    union { __hip_bfloat162 h; unsigned int u; } v; v.h = h; return v.u;
}

__device__ __forceinline__ floatx4 MFMA16(short8 a, short8 b, floatx4 c) {
    return __builtin_amdgcn_mfma_f32_16x16x32_bf16(a, b, c, 0, 0, 0);
}

// LDS-only barrier: lgkmcnt(0) only (vmcnt/expcnt maxed) + raw s_barrier.
__device__ __forceinline__ void bar_lds() {
    __builtin_amdgcn_s_waitcnt(0xc07f);
    __builtin_amdgcn_s_barrier();
}

// 8-seq swizzled LDS index: [chunk c(16)][seq m(8)][8 elems]
#define X8(c, m) ((((c) * 8) + ((m) ^ ((c) & 7))) * 8)
#define SP 264

// ---------------------------------------------------------------------------
// K0: canonicalize inputs -> bf16 (folding activation scales into weights),
// PLUS (merged) the lens/dtype work as 32 appended blocks.
// ---------------------------------------------------------------------------
struct ConvArgs {
    const void* src[25];
    int dstoff[25];
    int count[25];
    int cumblk[26];
    int mode[25];     // 0 none, 1 GRU (row<256 ? -L2E : 2L2E), 2 all 2L2E
    int rowdiv[25];
};

__global__ __launch_bounds__(256) void convert_kernel(ConvArgs a, ushort_t* __restrict__ dst,
                                                      const int* __restrict__ x,
                                                      int* wlens, int* slens, int* dmax,
                                                      int* flagp) {
    __shared__ int flag_lds;
    int tid = threadIdx.x, b = blockIdx.x;
    if (tid < 64) {
        unsigned int v = ((const unsigned int*)a.src[0])[tid];
        unsigned long long mball = __ballot(((v >> 7) & 0xFFu) > 0x7Bu);
        if (tid == 0) flag_lds = (__popcll(mball) > 8) ? 1 : 0;
    }
    __syncthreads();
    int flagv = flag_lds;
    int cblk = a.cumblk[25];

    if (b >= cblk) {
        int bb = b - cblk;
        if (bb == 0 && tid == 0) *flagp = flagv;
        if (tid < 64) {
            int s = tid;
            int last = 0;
            if (s < 32) {
                const int* tok = x + (bb * 32 + s) * 64;
                for (int t = 0; t < 64; t += 4) {
                    int4 v = *(const int4*)(tok + t);
                    if (v.x) last = t + 1;
                    if (v.y) last = t + 2;
                    if (v.z) last = t + 3;
                    if (v.w) last = t + 4;
                }
                wlens[bb * 32 + s] = last ? last : 1;
            }
            int len = (s < 32) ? (last ? last : 1) : 0;
            int lm = len;
            for (int off = 32; off; off >>= 1) lm = max(lm, __shfl_xor(lm, off));
            unsigned long long mask = __ballot(s < 32 && last > 0);
            if (s == 0) {
                slens[bb] = mask ? (63 - (int)__clzll(mask) + 1) : 1;
                dmax[bb] = lm;
            }
        }
        return;
    }

    int lo = 0, hi = 24;
    while (lo < hi) { int mid = (lo + hi + 1) >> 1; if (a.cumblk[mid] <= b) lo = mid; else hi = mid - 1; }
    int j = lo;
    int base = (b - a.cumblk[j]) * 2048 + tid * 8;
    if (base >= a.count[j]) return;
    ushort_t* out = dst + a.dstoff[j] + base;
    int m = a.mode[j], rd = a.rowdiv[j];
    float f[8];
    if (flagv) {
        const float* s = (const float*)a.src[j] + base;
        float4 v0 = *(const float4*)s;
        float4 v1 = *(const float4*)(s + 4);
        f[0] = v0.x; f[1] = v0.y; f[2] = v0.z; f[3] = v0.w;
        f[4] = v1.x; f[5] = v1.y; f[6] = v1.z; f[7] = v1.w;
    } else {
        const ushort_t* s = (const ushort_t*)a.src[j] + base;
        uint4 v = *(const uint4*)s;
        const ushort_t* u = (const ushort_t*)&v;
        #pragma unroll
        for (int e = 0; e < 8; ++e) f[e] = bf2f(u[e]);
    }
    union { ushort_t u[8]; uint4 v; } o;
    #pragma unroll
    for (int e = 0; e < 8; ++e) {
        float sc = 1.f;
        if (m == 2) sc = 2.f * L2E;
        else if (m == 1) sc = ((base + e) / rd < 256) ? -L2E : 2.f * L2E;
        o.u[e] = f2bf(f[e] * sc);
    }
    *(uint4*)out = o.v;
}

// ---------------------------------------------------------------------------
// Word-level BiGRU v5 (round-1 form — verified local optimum; do not touch):
// 8 seqs/block, grid (128,2) = 256 blocks. 512 thr / 8 waves.
// ---------------------------------------------------------------------------
__global__ __launch_bounds__(512, 2) void word_gru_kernel(
        const int* __restrict__ x, const ushort_t* __restrict__ emb,
        const ushort_t* __restrict__ Wih_f, const ushort_t* __restrict__ Whh_f,
        const ushort_t* __restrict__ bih_f, const ushort_t* __restrict__ bhh_f,
        const ushort_t* __restrict__ Wih_b, const ushort_t* __restrict__ Whh_b,
        const ushort_t* __restrict__ bih_b, const ushort_t* __restrict__ bhh_b,
        const int* __restrict__ lens, ushort_t* __restrict__ out) {
    const int T = 64;
    __shared__ ushort_t h_buf[2][1024];      // [chunk16][seq8][8] swizzled
    __shared__ float bsum_lds[256];
    __shared__ float bihn_lds[128];
    __shared__ float bhhn_lds[128];
    __shared__ int tok_lds[512];             // [t][s(8)]

    int tid = threadIdx.x;
    int d = blockIdx.y;
    int n0 = blockIdx.x * 8;
    const ushort_t* Wih = d ? Wih_b : Wih_f;
    const ushort_t* Whh = d ? Whh_b : Whh_f;
    const ushort_t* bih = d ? bih_b : bih_f;
    const ushort_t* bhh = d ? bhh_b : bhh_f;
    int lane = tid & 63, wave = tid >> 6;
    int l15 = lane & 15, l4 = (lane >> 4) & 3;
    int s8 = l15 & 7;                        // clamped seq index
    bool sv = l15 < 8;                       // this lane's col is valid
    int jt = wave * 16;
    int j0 = jt + l4 * 4;

    {
        int t = tid >> 3, s = tid & 7;
        tok_lds[tid] = x[(n0 + s) * 64 + t];
    }
    if (tid < 256) bsum_lds[tid] = bf2f(bih[tid]) + bf2f(bhh[tid]);
    else if (tid < 384) {
        bihn_lds[tid - 256] = bf2f(bih[tid]);
        bhhn_lds[tid - 256] = bf2f(bhh[tid]);
    }
    if (tid < 256) { uint2 z = {0u, 0u}; *(uint2*)&h_buf[0][tid * 4] = z; }

    short8 wr[4], wz[4], wn[4], ur[4], uz[4], un[4];
    #pragma unroll
    for (int kf = 0; kf < 4; ++kf) {
        int col = kf * 32 + l4 * 8;
        wr[kf] = *(const short8*)(Wih + (size_t)(jt + l15) * 128 + col);
        wz[kf] = *(const short8*)(Wih + (size_t)(128 + jt + l15) * 128 + col);
        wn[kf] = *(const short8*)(Wih + (size_t)(256 + jt + l15) * 128 + col);
        ur[kf] = *(const short8*)(Whh + (size_t)(jt + l15) * 128 + col);
        uz[kf] = *(const short8*)(Whh + (size_t)(128 + jt + l15) * 128 + col);
        un[kf] = *(const short8*)(Whh + (size_t)(256 + jt + l15) * 128 + col);
    }
    __syncthreads();

    floatx4 br  = *(floatx4*)&bsum_lds[j0];
    floatx4 bz  = *(floatx4*)&bsum_lds[128 + j0];
    floatx4 bxn = *(floatx4*)&bihn_lds[j0];
    floatx4 bhn = *(floatx4*)&bhhn_lds[j0];
    int lv = lens[n0 + s8];
    float hreg[4] = {0.f, 0.f, 0.f, 0.f};

    short8 xc[4], xn_[4];
    {
        int t0 = d ? (T - 1) : 0;
        size_t rb = (size_t)tok_lds[t0 * 8 + s8] * 128 + l4 * 8;
        #pragma unroll
        for (int kf = 0; kf < 4; ++kf)
            xc[kf] = *(const short8*)(emb + rb + kf * 32);
    }

    for (int ti = 0; ti < T; ++ti) {
        int t = d ? (T - 1 - ti) : ti;
        bool have_next = (ti + 1) < T;
        if (have_next) {
            int tn = d ? (T - 2 - ti) : (ti + 1);
            size_t rb = (size_t)tok_lds[tn * 8 + s8] * 128 + l4 * 8;
            #pragma unroll
            for (int kf = 0; kf < 4; ++kf)
                xn_[kf] = *(const short8*)(emb + rb + kf * 32);
        }
        short8 hb[4];
        #pragma unroll
        for (int kf = 0; kf < 4; ++kf)
            hb[kf] = *(const short8*)&h_buf[ti & 1][X8(kf * 4 + l4, s8)];
        floatx4 arx = br, azx = bz, axn = bxn;
        floatx4 arh = {0.f, 0.f, 0.f, 0.f}, azh = {0.f, 0.f, 0.f, 0.f}, ahn = bhn;
        #pragma unroll
        for (int kf = 0; kf < 4; ++kf) {
            arx = MFMA16(wr[kf], xc[kf], arx);
            azx = MFMA16(wz[kf], xc[kf], azx);
            axn = MFMA16(wn[kf], xc[kf], axn);
        }
        #pragma unroll
        for (int kf = 0; kf < 4; ++kf) {
            arh = MFMA16(ur[kf], hb[kf], arh);
            azh = MFMA16(uz[kf], hb[kf], azh);
            ahn = MFMA16(un[kf], hb[kf], ahn);
        }
        bool valid = t < lv;
        float hnew[4];
        #pragma unroll
        for (int i = 0; i < 4; ++i) {
            float r  = sig2(arx[i] + arh[i]);
            float z  = sig2(azx[i] + azh[i]);
            float nn = tanh2(axn[i] + r * ahn[i]);
            hnew[i] = valid ? (nn + z * (hreg[i] - nn)) : hreg[i];
            hreg[i] = hnew[i];
        }
        if (sv) {
            uint2 h2, o2;
            h2.x = packbf(hnew[0], hnew[1]);
            h2.y = packbf(hnew[2], hnew[3]);
            o2.x = valid ? h2.x : 0u;
            o2.y = valid ? h2.y : 0u;
            *(uint2*)&h_buf[(ti & 1) ^ 1][X8(j0 >> 3, s8) + (j0 & 7)] = h2;
            *(uint2*)(out + ((size_t)(n0 + s8) * T + t) * 256 + d * 128 + j0) = o2;
        }
        if (have_next) {
            #pragma unroll
            for (int kf = 0; kf < 4; ++kf) xc[kf] = xn_[kf];
        }
        bar_lds();
    }
}

// ---------------------------------------------------------------------------
// Word attention fused (proj W,b pre-scaled by 2·log2e). 4-acc epilogue.
// ---------------------------------------------------------------------------
__global__ __launch_bounds__(256) void word_attn_kernel(const ushort_t* __restrict__ wout,
                                                        const ushort_t* __restrict__ W,
                                                        const ushort_t* __restrict__ bias,
                                                        const ushort_t* __restrict__ ctx,
                                                        const int* __restrict__ dmax,
                                                        ushort_t* __restrict__ sent) {
    __shared__ ushort_t tile[64 * SP];
    __shared__ float bc[256];
    __shared__ float sc_lds[64];
    __shared__ float p_lds[64];
    int tid = threadIdx.x, g = blockIdx.x;
    for (int idx = tid; idx < 2048; idx += 256) {
        int row = idx >> 5, k0 = (idx & 31) * 8;
        *(uint4*)&tile[row * SP + k0] = *(const uint4*)(wout + ((size_t)g * 64 + row) * 256 + k0);
    }
    if (tid < 128) bc[tid] = bf2f(bias[tid]);
    else bc[tid] = bf2f(ctx[tid - 128]);
    __syncthreads();
    int lane = tid & 63, wave = tid >> 6;
    int l15 = lane & 15, l4 = (lane >> 4) & 3;
    short8 a[8];
    #pragma unroll
    for (int kf = 0; kf < 8; ++kf)
        a[kf] = *(const short8*)&tile[(wave * 16 + l15) * SP + kf * 32 + l4 * 8];
    floatx4 acc[8];
    #pragma unroll
    for (int nt = 0; nt < 8; ++nt) {
        floatx4 c = {0.f, 0.f, 0.f, 0.f};
        #pragma unroll
        for (int kf = 0; kf < 8; ++kf) {
            short8 b = *(const short8*)(W + (size_t)(nt * 16 + l15) * 256 + kf * 32 + l4 * 8);
            c = MFMA16(a[kf], b, c);
        }
        acc[nt] = c;
    }
    float s[4] = {0.f, 0.f, 0.f, 0.f};
    #pragma unroll
    for (int nt = 0; nt < 8; ++nt) {
        float bv = bc[nt * 16 + l15], cv = bc[128 + nt * 16 + l15];
        #pragma unroll
        for (int i = 0; i < 4; ++i)
            s[i] += tanh2(acc[nt][i] + bv) * cv;
    }
    #pragma unroll
    for (int i = 0; i < 4; ++i) {
        s[i] += __shfl_xor(s[i], 1);
        s[i] += __shfl_xor(s[i], 2);
        s[i] += __shfl_xor(s[i], 4);
        s[i] += __shfl_xor(s[i], 8);
    }
    if (l15 == 0) {
        #pragma unroll
        for (int i = 0; i < 4; ++i) sc_lds[wave * 16 + l4 * 4 + i] = s[i];
    }
    __syncthreads();
    if (tid < 64) {
        int ml = dmax[tid & 31];
        for (int off = 32; off; off >>= 1) ml = max(ml, __shfl_xor(ml, off));
        bool v = tid < ml;
        float sc = v ? sc_lds[tid] : -1e30f;
        float mx = sc;
        for (int off = 32; off; off >>= 1) mx = fmaxf(mx, __shfl_xor(mx, off));
        float e = v ? __expf(sc - mx) : 0.f;
        float sum = e;
        for (int off = 32; off; off >>= 1) sum += __shfl_xor(sum, off);
        p_lds[tid] = e * frcp(fmaxf(sum, 1e-30f));
    }
    __syncthreads();
    float a0 = 0.f, a1 = 0.f, a2 = 0.f, a3 = 0.f;
    for (int t = 0; t < 64; t += 4) {
        a0 += p_lds[t]     * bf2f(tile[t * SP + tid]);
        a1 += p_lds[t + 1] * bf2f(tile[(t + 1) * SP + tid]);
        a2 += p_lds[t + 2] * bf2f(tile[(t + 2) * SP + tid]);
        a3 += p_lds[t + 3] * bf2f(tile[(t + 3) * SP + tid]);
    }
    sent[(size_t)g * 256 + tid] = f2bf((a0 + a1) + (a2 + a3));
}

// ---------------------------------------------------------------------------
// Cooperative TAIL kernel: phase0 spt GEMM (192 tile-engines, verbatim math)
// -> grid.sync -> phase1 sent_gru (blocks 0-7, round-1 body verbatim)
// -> grid.sync -> phase2 sent_attn+FC (blocks 0-31).
// Tests the inter-dispatch-gap hypothesis: removes 2 kernel boundaries.
// ---------------------------------------------------------------------------
struct TailArgs {
    const ushort_t* sent;
    const ushort_t* Bf; const ushort_t* biasf; ushort_t* Tf;
    const ushort_t* Bb; const ushort_t* biasb; ushort_t* Tb;
    const ushort_t* Whh_f; const ushort_t* Whh_b;
    const ushort_t* bhh_f; const ushort_t* bhh_b;
    const int* slens; ushort_t* sout;
    const ushort_t* W; const ushort_t* bias; const ushort_t* ctx;
    const ushort_t* fcW; const ushort_t* fcb;
    const int* flagp; void* outp;
};

__global__ __launch_bounds__(512, 1) void tail_kernel(TailArgs ta) {
    namespace cg = cooperative_groups;
    cg::grid_group grid = cg::this_grid();
    __shared__ __align__(16) char smraw[65536];
    int tid = threadIdx.x;
    int b = blockIdx.x;
    int lane = tid & 63, wave = tid >> 6;
    int l15 = lane & 15, l4 = (lane >> 4) & 3;

    // ---------------- Phase 0: spt GEMM (all 192 blocks) ----------------
    {
        ushort_t* As = (ushort_t*)smraw;          // 64*256
        ushort_t* Bs = As + 64 * 256;
        const int K = 256;
        int by = b / 16, bx = b % 16;
        bool sb = by >= 6;
        int n0 = (sb ? by - 6 : by) * 64;
        const ushort_t* B = sb ? ta.Bb : ta.Bf;
        const ushort_t* bias = sb ? ta.biasb : ta.biasf;
        ushort_t* Tp = sb ? ta.Tb : ta.Tf;
        int m0 = bx * 64;
        for (int idx = tid; idx < 2048; idx += 512) {
            int m = idx & 63, c = idx >> 6;
            *(uint4*)&As[(c * 64 + m) * 8] = *(const uint4*)(ta.sent + (size_t)(m0 + m) * K + c * 8);
        }
        for (int idx = tid; idx < 2048; idx += 512) {
            int n = idx & 63, c = idx >> 6;
            *(uint4*)&Bs[(c * 64 + n) * 8] = *(const uint4*)(B + (size_t)(n0 + n) * K + c * 8);
        }
        __syncthreads();
        if (wave < 4) {
            int wm = (wave & 1) * 32, wn = (wave >> 1) * 32;
            floatx4 acc[2][2] = {};
            for (int kf = 0; kf < 8; ++kf) {
                int c = kf * 4 + l4;
                short8 a0 = *(const short8*)&As[(c * 64 + wm + l15) * 8];
                short8 a1 = *(const short8*)&As[(c * 64 + wm + 16 + l15) * 8];
                short8 b0 = *(const short8*)&Bs[(c * 64 + wn + l15) * 8];
                short8 b1 = *(const short8*)&Bs[(c * 64 + wn + 16 + l15) * 8];
                acc[0][0] = MFMA16(a0, b0, acc[0][0]);
                acc[0][1] = MFMA16(a0, b1, acc[0][1]);
                acc[1][0] = MFMA16(a1, b0, acc[1][0]);
                acc[1][1] = MFMA16(a1, b1, acc[1][1]);
            }
            for (int nt = 0; nt < 2; ++nt) {
                int n = n0 + wn + nt * 16 + l15;
                float bv = bf2f(bias[n]);
                int jc = n >> 2, ji = n & 3;
                for (int mt = 0; mt < 2; ++mt) {
                    int mbase = m0 + wm + mt * 16 + l4 * 4;
                    #pragma unroll
                    for (int i = 0; i < 4; ++i) {
                        int m = mbase + i;
                        int doc = m >> 5, t = m & 31;
                        size_t dst = ((size_t)((doc >> 4) * 32 + t) * 96 + jc) * 64
                                   + (doc & 15) * 4 + ji;
                        Tp[dst] = f2bf(acc[mt][nt][i] + bv);
                    }
                }
            }
        }
    }
    __threadfence();
    grid.sync();

    // ---------------- Phase 1: sent_gru (blocks 0-7) ----------------
    if (b < 8) {
        const int T = 32;
        ushort_t (*h_buf)[1024] = (ushort_t (*)[1024])smraw;      // 2x1024 ushort
        float* bhh_lds = (float*)(smraw + 4096);                  // 384 floats
        int d = b >> 2;
        int bx = b & 3;
        int n0 = bx * 8;
        const ushort_t* spT = d ? ta.Tb : ta.Tf;
        const ushort_t* Whh = d ? ta.Whh_b : ta.Whh_f;
        const ushort_t* bhh = d ? ta.bhh_b : ta.bhh_f;
        int s8 = l15 & 7;
        bool sv = l15 < 8;
        int jt = wave * 16;
        int j0 = jt + l4 * 4;
        int jc = j0 >> 2;

        if (tid < 384) bhh_lds[tid] = bf2f(bhh[tid]);
        if (tid < 256) { uint2 z = {0u, 0u}; *(uint2*)&h_buf[0][tid * 4] = z; }

        short8 ur[4], uz[4], un[4];
        #pragma unroll
        for (int kf = 0; kf < 4; ++kf) {
            int col = kf * 32 + l4 * 8;
            ur[kf] = *(const short8*)(Whh + (size_t)(jt + l15) * 128 + col);
            uz[kf] = *(const short8*)(Whh + (size_t)(128 + jt + l15) * 128 + col);
            un[kf] = *(const short8*)(Whh + (size_t)(256 + jt + l15) * 128 + col);
        }
        __syncthreads();

        floatx4 br  = *(floatx4*)&bhh_lds[j0];
        floatx4 bz  = *(floatx4*)&bhh_lds[128 + j0];
        floatx4 bhn = *(floatx4*)&bhh_lds[256 + j0];
        int lv = ta.slens[n0 + s8];
        float hreg[4] = {0.f, 0.f, 0.f, 0.f};

        const ushort_t* sp = spT + (size_t)((bx >> 1) * 32) * 96 * 64
                           + ((bx & 1) * 8 + s8) * 4;
        ushort4 xr_c, xz_c, xn_c, xr_n, xz_n, xn_n;
        {
            int t0 = d ? (T - 1) : 0;
            size_t rb = (size_t)t0 * 96 * 64;
            xr_c = *(const ushort4*)(sp + rb + (size_t)jc * 64);
            xz_c = *(const ushort4*)(sp + rb + (size_t)(32 + jc) * 64);
            xn_c = *(const ushort4*)(sp + rb + (size_t)(64 + jc) * 64);
        }

        for (int ti = 0; ti < T; ++ti) {
            int t = d ? (T - 1 - ti) : ti;
            int cur = ti & 1;
            bool have_next = (ti + 1) < T;
            if (have_next) {
                int tn = d ? (T - 2 - ti) : (ti + 1);
                size_t rb = (size_t)tn * 96 * 64;
                xr_n = *(const ushort4*)(sp + rb + (size_t)jc * 64);
                xz_n = *(const ushort4*)(sp + rb + (size_t)(32 + jc) * 64);
                xn_n = *(const ushort4*)(sp + rb + (size_t)(64 + jc) * 64);
            }
            floatx4 ar = br, az = bz, ahn = bhn;
            #pragma unroll
            for (int kf = 0; kf < 4; ++kf) {
                short8 hb = *(const short8*)&h_buf[cur][X8(kf * 4 + l4, s8)];
                ar  = MFMA16(ur[kf], hb, ar);
                az  = MFMA16(uz[kf], hb, az);
                ahn = MFMA16(un[kf], hb, ahn);
            }
            float xr[4] = {bf2f(xr_c.x), bf2f(xr_c.y), bf2f(xr_c.z), bf2f(xr_c.w)};
            float xz[4] = {bf2f(xz_c.x), bf2f(xz_c.y), bf2f(xz_c.z), bf2f(xz_c.w)};
            float xn[4] = {bf2f(xn_c.x), bf2f(xn_c.y), bf2f(xn_c.z), bf2f(xn_c.w)};
            bool valid = t < lv;
            float hnew[4];
            #pragma unroll
            for (int i = 0; i < 4; ++i) {
                float r  = sig2(xr[i] + ar[i]);
                float z  = sig2(xz[i] + az[i]);
                float nn = tanh2(xn[i] + r * ahn[i]);
                hnew[i] = valid ? (nn + z * (hreg[i] - nn)) : hreg[i];
                hreg[i] = hnew[i];
            }
            if (sv) {
                uint2 h2, o2;
                h2.x = packbf(hnew[0], hnew[1]);
                h2.y = packbf(hnew[2], hnew[3]);
                o2.x = valid ? h2.x : 0u;
                o2.y = valid ? h2.y : 0u;
                *(uint2*)&h_buf[cur ^ 1][X8(j0 >> 3, s8) + (j0 & 7)] = h2;
                *(uint2*)(ta.sout + ((size_t)(n0 + s8) * T + t) * 256 + d * 128 + j0) = o2;
            }
            if (have_next) { xr_c = xr_n; xz_c = xz_n; xn_c = xn_n; }
            bar_lds();
        }
    }
    __threadfence();
    grid.sync();

    // ---------------- Phase 2: sent_attn + FC (blocks 0-31) ----------------
    if (b < 32) {
        int g = b;
        ushort_t* tile = (ushort_t*)smraw;                 // 32*SP ushorts = 16896 B
        float* bc     = (float*)(smraw + 16896);           // 256 f
        float* sc_lds = (float*)(smraw + 17920);           // 32 f
        float* p_lds  = (float*)(smraw + 18048);           // 32 f
        float* dv     = (float*)(smraw + 18176);           // 256 f
        for (int idx = tid; idx < 1024; idx += 512) {
            int row = idx >> 5, k0 = (idx & 31) * 8;
            *(uint4*)&tile[row * SP + k0] = *(const uint4*)(ta.sout + ((size_t)g * 32 + row) * 256 + k0);
        }
        if (tid < 128) bc[tid] = bf2f(ta.bias[tid]);
        else if (tid < 256) bc[tid] = bf2f(ta.ctx[tid - 128]);
        __syncthreads();
        if (wave < 2) {
            short8 a[8];
            #pragma unroll
            for (int kf = 0; kf < 8; ++kf)
                a[kf] = *(const short8*)&tile[(wave * 16 + l15) * SP + kf * 32 + l4 * 8];
            floatx4 acc[8];
            #pragma unroll
            for (int nt = 0; nt < 8; ++nt) {
                floatx4 c = {0.f, 0.f, 0.f, 0.f};
                #pragma unroll
                for (int kf = 0; kf < 8; ++kf) {
                    short8 bb = *(const short8*)(ta.W + (size_t)(nt * 16 + l15) * 256 + kf * 32 + l4 * 8);
                    c = MFMA16(a[kf], bb, c);
                }
                acc[nt] = c;
            }
            float s[4] = {0.f, 0.f, 0.f, 0.f};
            #pragma unroll
            for (int nt = 0; nt < 8; ++nt) {
                float bv = bc[nt * 16 + l15], cv = bc[128 + nt * 16 + l15];
                #pragma unroll
                for (int i = 0; i < 4; ++i)
                    s[i] += tanh2(acc[nt][i] + bv) * cv;
            }
            #pragma unroll
            for (int i = 0; i < 4; ++i) {
                s[i] += __shfl_xor(s[i], 1);
                s[i] += __shfl_xor(s[i], 2);
                s[i] += __shfl_xor(s[i], 4);
                s[i] += __shfl_xor(s[i], 8);
            }
            if (l15 == 0) {
                #pragma unroll
                for (int i = 0; i < 4; ++i) sc_lds[wave * 16 + l4 * 4 + i] = s[i];
            }
        }
        __syncthreads();
        if (tid < 32) {
            int ml = ta.slens[tid];
            for (int off = 16; off; off >>= 1) ml = max(ml, __shfl_xor(ml, off, 32));
            bool v = tid < ml;
            float sc = v ? sc_lds[tid] : -1e30f;
            float mx = sc;
            for (int off = 16; off; off >>= 1) mx = fmaxf(mx, __shfl_xor(mx, off, 32));
            float e = v ? __expf(sc - mx) : 0.f;
            float sum = e;
            for (int off = 16; off; off >>= 1) sum += __shfl_xor(sum, off, 32);
            p_lds[tid] = e * frcp(fmaxf(sum, 1e-30f));
        }
        __syncthreads();
        if (tid < 256) {
            float acc2 = 0.f;
            for (int t = 0; t < 32; ++t) acc2 += p_lds[t] * bf2f(tile[t * SP + tid]);
            dv[tid] = acc2;
        }
        __syncthreads();
        if (tid < 256) {
            int c = tid >> 5, q0 = (tid & 31) * 8;
            float partial = 0.f;
            #pragma unroll
            for (int q = 0; q < 8; ++q)
                partial += dv[q0 + q] * bf2f(ta.fcW[(size_t)c * 256 + q0 + q]);
            for (int off = 16; off; off >>= 1) partial += __shfl_xor(partial, off, 32);
            if ((tid & 31) == 0) {
                float v = partial + bf2f(ta.fcb[c]);
                if (*ta.flagp) ((float*)ta.outp)[g * 8 + c] = v;
                else          ((ushort_t*)ta.outp)[g * 8 + c] = f2bf(v);
            }
        }
    }
}

// ---------------------------------------------------------------------------
extern "C" void kernel_launch(void* const* d_in, const int* in_sizes, int n_in,
                              void* d_out, int out_size, void* d_ws, size_t ws_size,
                              hipStream_t stream) {
    const int* x = (const int*)d_in[0];
    char* ws = (char*)d_ws;

    const size_t O_CONV = 0;            // canonical bf16 inputs (~14 MB)
    const size_t O_WOUT = 14680064;     // [65536,256] bf16  33.55 MB
    const size_t O_SENT = 48234496;     // [1024,256] bf16
    const size_t O_SOUT = 48758784;     // [1024,256] bf16
    const size_t O_SPTF = 49283072;     // spT fwd 1.5MB
    const size_t O_SPTB = 50855936;     // spT bwd
    const size_t O_LENS = 52428800;
    const size_t O_SLEN = 52432896;
    const size_t O_DMAX = 52433024;
    const size_t O_FLAG = 52433152;

    ushort_t* conv = (ushort_t*)(ws + O_CONV);
    ushort_t* wout = (ushort_t*)(ws + O_WOUT);
    ushort_t* sent = (ushort_t*)(ws + O_SENT);
    ushort_t* sout = (ushort_t*)(ws + O_SOUT);
    ushort_t* sptf = (ushort_t*)(ws + O_SPTF);
    ushort_t* sptb = (ushort_t*)(ws + O_SPTB);
    int* wlens = (int*)(ws + O_LENS);
    int* slens = (int*)(ws + O_SLEN);
    int* dmax  = (int*)(ws + O_DMAX);
    int* flag  = (int*)(ws + O_FLAG);

    static const int kMode[25]   = {0, 1,1,1,1, 1,1,1,1, 1,1,1,1, 1,1,1,1, 2,2,0, 2,2,0, 0,0};
    static const int kRowdiv[25] = {1, 128,128,1,1, 128,128,1,1, 256,128,1,1, 256,128,1,1,
                                    1,1,1, 1,1,1, 1,1};

    ConvArgs ca;
    ushort_t* cw[25];
    int off = 0, blk = 0;
    for (int i = 1; i <= 25; ++i) {
        int j = i - 1;
        int cnt = in_sizes[i];
        ca.src[j] = d_in[i];
        ca.dstoff[j] = off;
        ca.count[j] = cnt;
        ca.cumblk[j] = blk;
        ca.mode[j] = kMode[j];
        ca.rowdiv[j] = kRowdiv[j];
        cw[j] = conv + off;
        off += cnt;
        blk += (cnt + 2047) / 2048;
    }
    ca.cumblk[25] = blk;

    // 1) canonicalize + lens + dtype flag (merged; lens = 32 extra blocks)
    convert_kernel<<<blk + 32, 256, 0, stream>>>(ca, conv, x, wlens, slens, dmax, flag);
    // 2) word BiGRU (8 seqs/block, 256 blocks -> all CUs)
    word_gru_kernel<<<dim3(128, 2), 512, 0, stream>>>(
        x, cw[0],
        cw[1], cw[2], cw[3], cw[4],
        cw[5], cw[6], cw[7], cw[8],
        wlens, wout);
    // 3) word attention -> sent
    word_attn_kernel<<<1024, 256, 0, stream>>>(wout, cw[17], cw[18], cw[19], dmax, sent);
    // 4) cooperative tail: spt GEMM -> sent BiGRU -> sent attn+FC
    TailArgs ta;
    ta.sent = sent;
    ta.Bf = cw[9];  ta.biasf = cw[11]; ta.Tf = sptf;
    ta.Bb = cw[13]; ta.biasb = cw[15]; ta.Tb = sptb;
    ta.Whh_f = cw[10]; ta.Whh_b = cw[14];
    ta.bhh_f = cw[12]; ta.bhh_b = cw[16];
    ta.slens = slens; ta.sout = sout;
    ta.W = cw[20]; ta.bias = cw[21]; ta.ctx = cw[22];
    ta.fcW = cw[23]; ta.fcb = cw[24];
    ta.flagp = flag; ta.outp = d_out;
    void* kargs[] = { &ta };
    hipLaunchCooperativeKernel((void*)tail_kernel, dim3(192), dim3(512),
                               kargs, 0, stream);
    (void)n_in; (void)out_size; (void)ws_size;
}

// Round 8
// 357.690 us; speedup vs baseline: 1.2263x; 1.2263x over previous
//
#include <hip/hip_runtime.h>
#include <hip/hip_bf16.h>

typedef unsigned short ushort_t;
typedef __attribute__((ext_vector_type(4))) float floatx4;
typedef __attribute__((ext_vector_type(8))) short short8;

#define L2E 1.4426950408889634f

__device__ __forceinline__ float bf2f(ushort_t u) {
    union { unsigned int i; float f; } v; v.i = ((unsigned int)u) << 16; return v.f;
}
__device__ __forceinline__ ushort_t f2bf(float f) {
    union { float f; unsigned int i; } v; v.f = f;
    unsigned int i = v.i;
    i += 0x7fffu + ((i >> 16) & 1u);            // RNE
    return (ushort_t)(i >> 16);
}
__device__ __forceinline__ float fexp2(float x) {
#if __has_builtin(__builtin_amdgcn_exp2f)
    return __builtin_amdgcn_exp2f(x);
#else
    return __expf(x * 0.6931471805599453f);
#endif
}
__device__ __forceinline__ float frcp(float x) {
#if __has_builtin(__builtin_amdgcn_rcpf)
    return __builtin_amdgcn_rcpf(x);
#else
    return 1.f / x;
#endif
}
// σ(x) with pre-scaled input a = −log2e·x ; tanh(x) with y = 2·log2e·x.
__device__ __forceinline__ float sig2(float a)  { return frcp(1.f + fexp2(a)); }
__device__ __forceinline__ float tanh2(float y) { return 1.f - 2.f * frcp(1.f + fexp2(y)); }

__device__ __forceinline__ unsigned int packbf(float a, float b) {
    float2 t; t.x = a; t.y = b;
    __hip_bfloat162 h = __float22bfloat162_rn(t);
    union { __hip_bfloat162 h; unsigned int u; } v; v.h = h; return v.u;
}

__device__ __forceinline__ floatx4 MFMA16(short8 a, short8 b, floatx4 c) {
    return __builtin_amdgcn_mfma_f32_16x16x32_bf16(a, b, c, 0, 0, 0);
}

// LDS-only barrier: lgkmcnt(0) only (vmcnt/expcnt maxed) + raw s_barrier.
__device__ __forceinline__ void bar_lds() {
    __builtin_amdgcn_s_waitcnt(0xc07f);
    __builtin_amdgcn_s_barrier();
}

// 8-seq swizzled LDS index: [chunk c(16)][seq m(8)][8 elems]
#define X8(c, m) ((((c) * 8) + ((m) ^ ((c) & 7))) * 8)
#define SP 264

// ---------------------------------------------------------------------------
// K0: canonicalize inputs -> bf16 (folding activation scales into weights),
// PLUS (merged) the lens/dtype work as 32 appended blocks.
// ---------------------------------------------------------------------------
struct ConvArgs {
    const void* src[25];
    int dstoff[25];
    int count[25];
    int cumblk[26];
    int mode[25];     // 0 none, 1 GRU (row<256 ? -L2E : 2L2E), 2 all 2L2E
    int rowdiv[25];
};

__global__ __launch_bounds__(256) void convert_kernel(ConvArgs a, ushort_t* __restrict__ dst,
                                                      const int* __restrict__ x,
                                                      int* wlens, int* slens, int* dmax,
                                                      int* flagp) {
    __shared__ int flag_lds;
    int tid = threadIdx.x, b = blockIdx.x;
    if (tid < 64) {
        unsigned int v = ((const unsigned int*)a.src[0])[tid];
        unsigned long long mball = __ballot(((v >> 7) & 0xFFu) > 0x7Bu);
        if (tid == 0) flag_lds = (__popcll(mball) > 8) ? 1 : 0;
    }
    __syncthreads();
    int flagv = flag_lds;
    int cblk = a.cumblk[25];

    if (b >= cblk) {
        int bb = b - cblk;
        if (bb == 0 && tid == 0) *flagp = flagv;
        if (tid < 64) {
            int s = tid;
            int last = 0;
            if (s < 32) {
                const int* tok = x + (bb * 32 + s) * 64;
                for (int t = 0; t < 64; t += 4) {
                    int4 v = *(const int4*)(tok + t);
                    if (v.x) last = t + 1;
                    if (v.y) last = t + 2;
                    if (v.z) last = t + 3;
                    if (v.w) last = t + 4;
                }
                wlens[bb * 32 + s] = last ? last : 1;
            }
            int len = (s < 32) ? (last ? last : 1) : 0;
            int lm = len;
            for (int off = 32; off; off >>= 1) lm = max(lm, __shfl_xor(lm, off));
            unsigned long long mask = __ballot(s < 32 && last > 0);
            if (s == 0) {
                slens[bb] = mask ? (63 - (int)__clzll(mask) + 1) : 1;
                dmax[bb] = lm;
            }
        }
        return;
    }

    int lo = 0, hi = 24;
    while (lo < hi) { int mid = (lo + hi + 1) >> 1; if (a.cumblk[mid] <= b) lo = mid; else hi = mid - 1; }
    int j = lo;
    int base = (b - a.cumblk[j]) * 2048 + tid * 8;
    if (base >= a.count[j]) return;
    ushort_t* out = dst + a.dstoff[j] + base;
    int m = a.mode[j], rd = a.rowdiv[j];
    float f[8];
    if (flagv) {
        const float* s = (const float*)a.src[j] + base;
        float4 v0 = *(const float4*)s;
        float4 v1 = *(const float4*)(s + 4);
        f[0] = v0.x; f[1] = v0.y; f[2] = v0.z; f[3] = v0.w;
        f[4] = v1.x; f[5] = v1.y; f[6] = v1.z; f[7] = v1.w;
    } else {
        const ushort_t* s = (const ushort_t*)a.src[j] + base;
        uint4 v = *(const uint4*)s;
        const ushort_t* u = (const ushort_t*)&v;
        #pragma unroll
        for (int e = 0; e < 8; ++e) f[e] = bf2f(u[e]);
    }
    union { ushort_t u[8]; uint4 v; } o;
    #pragma unroll
    for (int e = 0; e < 8; ++e) {
        float sc = 1.f;
        if (m == 2) sc = 2.f * L2E;
        else if (m == 1) sc = ((base + e) / rd < 256) ? -L2E : 2.f * L2E;
        o.u[e] = f2bf(f[e] * sc);
    }
    *(uint4*)out = o.v;
}

// ---------------------------------------------------------------------------
// Word-level BiGRU v5 (round-1 form — verified local optimum; do not touch):
// 8 seqs/block, grid (128,2) = 256 blocks. 512 thr / 8 waves.
// ---------------------------------------------------------------------------
__global__ __launch_bounds__(512, 2) void word_gru_kernel(
        const int* __restrict__ x, const ushort_t* __restrict__ emb,
        const ushort_t* __restrict__ Wih_f, const ushort_t* __restrict__ Whh_f,
        const ushort_t* __restrict__ bih_f, const ushort_t* __restrict__ bhh_f,
        const ushort_t* __restrict__ Wih_b, const ushort_t* __restrict__ Whh_b,
        const ushort_t* __restrict__ bih_b, const ushort_t* __restrict__ bhh_b,
        const int* __restrict__ lens, ushort_t* __restrict__ out) {
    const int T = 64;
    __shared__ ushort_t h_buf[2][1024];      // [chunk16][seq8][8] swizzled
    __shared__ float bsum_lds[256];
    __shared__ float bihn_lds[128];
    __shared__ float bhhn_lds[128];
    __shared__ int tok_lds[512];             // [t][s(8)]

    int tid = threadIdx.x;
    int d = blockIdx.y;
    int n0 = blockIdx.x * 8;
    const ushort_t* Wih = d ? Wih_b : Wih_f;
    const ushort_t* Whh = d ? Whh_b : Whh_f;
    const ushort_t* bih = d ? bih_b : bih_f;
    const ushort_t* bhh = d ? bhh_b : bhh_f;
    int lane = tid & 63, wave = tid >> 6;
    int l15 = lane & 15, l4 = (lane >> 4) & 3;
    int s8 = l15 & 7;                        // clamped seq index
    bool sv = l15 < 8;                       // this lane's col is valid
    int jt = wave * 16;
    int j0 = jt + l4 * 4;

    {
        int t = tid >> 3, s = tid & 7;
        tok_lds[tid] = x[(n0 + s) * 64 + t];
    }
    if (tid < 256) bsum_lds[tid] = bf2f(bih[tid]) + bf2f(bhh[tid]);
    else if (tid < 384) {
        bihn_lds[tid - 256] = bf2f(bih[tid]);
        bhhn_lds[tid - 256] = bf2f(bhh[tid]);
    }
    if (tid < 256) { uint2 z = {0u, 0u}; *(uint2*)&h_buf[0][tid * 4] = z; }

    short8 wr[4], wz[4], wn[4], ur[4], uz[4], un[4];
    #pragma unroll
    for (int kf = 0; kf < 4; ++kf) {
        int col = kf * 32 + l4 * 8;
        wr[kf] = *(const short8*)(Wih + (size_t)(jt + l15) * 128 + col);
        wz[kf] = *(const short8*)(Wih + (size_t)(128 + jt + l15) * 128 + col);
        wn[kf] = *(const short8*)(Wih + (size_t)(256 + jt + l15) * 128 + col);
        ur[kf] = *(const short8*)(Whh + (size_t)(jt + l15) * 128 + col);
        uz[kf] = *(const short8*)(Whh + (size_t)(128 + jt + l15) * 128 + col);
        un[kf] = *(const short8*)(Whh + (size_t)(256 + jt + l15) * 128 + col);
    }
    __syncthreads();

    floatx4 br  = *(floatx4*)&bsum_lds[j0];
    floatx4 bz  = *(floatx4*)&bsum_lds[128 + j0];
    floatx4 bxn = *(floatx4*)&bihn_lds[j0];
    floatx4 bhn = *(floatx4*)&bhhn_lds[j0];
    int lv = lens[n0 + s8];
    float hreg[4] = {0.f, 0.f, 0.f, 0.f};

    short8 xc[4], xn_[4];
    {
        int t0 = d ? (T - 1) : 0;
        size_t rb = (size_t)tok_lds[t0 * 8 + s8] * 128 + l4 * 8;
        #pragma unroll
        for (int kf = 0; kf < 4; ++kf)
            xc[kf] = *(const short8*)(emb + rb + kf * 32);
    }

    for (int ti = 0; ti < T; ++ti) {
        int t = d ? (T - 1 - ti) : ti;
        bool have_next = (ti + 1) < T;
        if (have_next) {
            int tn = d ? (T - 2 - ti) : (ti + 1);
            size_t rb = (size_t)tok_lds[tn * 8 + s8] * 128 + l4 * 8;
            #pragma unroll
            for (int kf = 0; kf < 4; ++kf)
                xn_[kf] = *(const short8*)(emb + rb + kf * 32);
        }
        short8 hb[4];
        #pragma unroll
        for (int kf = 0; kf < 4; ++kf)
            hb[kf] = *(const short8*)&h_buf[ti & 1][X8(kf * 4 + l4, s8)];
        floatx4 arx = br, azx = bz, axn = bxn;
        floatx4 arh = {0.f, 0.f, 0.f, 0.f}, azh = {0.f, 0.f, 0.f, 0.f}, ahn = bhn;
        #pragma unroll
        for (int kf = 0; kf < 4; ++kf) {
            arx = MFMA16(wr[kf], xc[kf], arx);
            azx = MFMA16(wz[kf], xc[kf], azx);
            axn = MFMA16(wn[kf], xc[kf], axn);
        }
        #pragma unroll
        for (int kf = 0; kf < 4; ++kf) {
            arh = MFMA16(ur[kf], hb[kf], arh);
            azh = MFMA16(uz[kf], hb[kf], azh);
            ahn = MFMA16(un[kf], hb[kf], ahn);
        }
        bool valid = t < lv;
        float hnew[4];
        #pragma unroll
        for (int i = 0; i < 4; ++i) {
            float r  = sig2(arx[i] + arh[i]);
            float z  = sig2(azx[i] + azh[i]);
            float nn = tanh2(axn[i] + r * ahn[i]);
            hnew[i] = valid ? (nn + z * (hreg[i] - nn)) : hreg[i];
            hreg[i] = hnew[i];
        }
        if (sv) {
            uint2 h2, o2;
            h2.x = packbf(hnew[0], hnew[1]);
            h2.y = packbf(hnew[2], hnew[3]);
            o2.x = valid ? h2.x : 0u;
            o2.y = valid ? h2.y : 0u;
            *(uint2*)&h_buf[(ti & 1) ^ 1][X8(j0 >> 3, s8) + (j0 & 7)] = h2;
            *(uint2*)(out + ((size_t)(n0 + s8) * T + t) * 256 + d * 128 + j0) = o2;
        }
        if (have_next) {
            #pragma unroll
            for (int kf = 0; kf < 4; ++kf) xc[kf] = xn_[kf];
        }
        bar_lds();
    }
}

// ---------------------------------------------------------------------------
// Sentence xp GEMM -> transposed layout spT (weights pre-scaled at convert).
// 192 blocks — keep wide; 8-block fusion cost +56 µs (round-5 lesson).
// ---------------------------------------------------------------------------
__global__ __launch_bounds__(256) void spt_gemm_kernel(const ushort_t* __restrict__ A,
                                                       const ushort_t* __restrict__ Bf_,
                                                       const ushort_t* __restrict__ biasf,
                                                       ushort_t* __restrict__ Tf_,
                                                       const ushort_t* __restrict__ Bb_,
                                                       const ushort_t* __restrict__ biasb,
                                                       ushort_t* __restrict__ Tb_) {
    __shared__ ushort_t As[64 * 256];
    __shared__ ushort_t Bs[64 * 256];
    const int K = 256;
    int tid = threadIdx.x;
    int by = blockIdx.y;
    bool sb = by >= 6;
    int n0 = (sb ? by - 6 : by) * 64;
    const ushort_t* B = sb ? Bb_ : Bf_;
    const ushort_t* bias = sb ? biasb : biasf;
    ushort_t* Tp = sb ? Tb_ : Tf_;
    int m0 = blockIdx.x * 64;
    for (int idx = tid; idx < 2048; idx += 256) {
        int m = idx & 63, c = idx >> 6;
        *(uint4*)&As[(c * 64 + m) * 8] = *(const uint4*)(A + (size_t)(m0 + m) * K + c * 8);
    }
    for (int idx = tid; idx < 2048; idx += 256) {
        int n = idx & 63, c = idx >> 6;
        *(uint4*)&Bs[(c * 64 + n) * 8] = *(const uint4*)(B + (size_t)(n0 + n) * K + c * 8);
    }
    __syncthreads();
    int lane = tid & 63, wave = tid >> 6;
    int wm = (wave & 1) * 32, wn = (wave >> 1) * 32;
    int l15 = lane & 15, l4 = lane >> 4;
    floatx4 acc[2][2] = {};
    for (int kf = 0; kf < 8; ++kf) {
        int c = kf * 4 + l4;
        short8 a0 = *(const short8*)&As[(c * 64 + wm + l15) * 8];
        short8 a1 = *(const short8*)&As[(c * 64 + wm + 16 + l15) * 8];
        short8 b0 = *(const short8*)&Bs[(c * 64 + wn + l15) * 8];
        short8 b1 = *(const short8*)&Bs[(c * 64 + wn + 16 + l15) * 8];
        acc[0][0] = MFMA16(a0, b0, acc[0][0]);
        acc[0][1] = MFMA16(a0, b1, acc[0][1]);
        acc[1][0] = MFMA16(a1, b0, acc[1][0]);
        acc[1][1] = MFMA16(a1, b1, acc[1][1]);
    }
    for (int nt = 0; nt < 2; ++nt) {
        int n = n0 + wn + nt * 16 + l15;
        float bv = bf2f(bias[n]);
        int jc = n >> 2, ji = n & 3;
        for (int mt = 0; mt < 2; ++mt) {
            int mbase = m0 + wm + mt * 16 + l4 * 4;
            #pragma unroll
            for (int i = 0; i < 4; ++i) {
                int m = mbase + i;
                int doc = m >> 5, t = m & 31;
                size_t dst = ((size_t)((doc >> 4) * 32 + t) * 96 + jc) * 64
                           + (doc & 15) * 4 + ji;
                Tp[dst] = f2bf(acc[mt][nt][i] + bv);
            }
        }
    }
}

// ---------------------------------------------------------------------------
// Sentence-level BiGRU: 8 docs/block, grid (4,2) = 8 blocks. (round-1 form)
// ---------------------------------------------------------------------------
__global__ __launch_bounds__(512, 2) void sent_gru_kernel(
        const ushort_t* __restrict__ spT_f, const ushort_t* __restrict__ spT_b,
        const ushort_t* __restrict__ Whh_f, const ushort_t* __restrict__ Whh_b,
        const ushort_t* __restrict__ bhh_f, const ushort_t* __restrict__ bhh_b,
        const int* __restrict__ lens, ushort_t* __restrict__ out) {
    const int T = 32;
    __shared__ ushort_t h_buf[2][1024];
    __shared__ float bhh_lds[384];

    int tid = threadIdx.x;
    int d = blockIdx.y;
    int bx = blockIdx.x;
    int n0 = bx * 8;
    const ushort_t* spT = d ? spT_b : spT_f;
    const ushort_t* Whh = d ? Whh_b : Whh_f;
    const ushort_t* bhh = d ? bhh_b : bhh_f;
    int lane = tid & 63, wave = tid >> 6;
    int l15 = lane & 15, l4 = (lane >> 4) & 3;
    int s8 = l15 & 7;
    bool sv = l15 < 8;
    int jt = wave * 16;
    int j0 = jt + l4 * 4;
    int jc = j0 >> 2;

    if (tid < 384) bhh_lds[tid] = bf2f(bhh[tid]);
    if (tid < 256) { uint2 z = {0u, 0u}; *(uint2*)&h_buf[0][tid * 4] = z; }

    short8 ur[4], uz[4], un[4];
    #pragma unroll
    for (int kf = 0; kf < 4; ++kf) {
        int col = kf * 32 + l4 * 8;
        ur[kf] = *(const short8*)(Whh + (size_t)(jt + l15) * 128 + col);
        uz[kf] = *(const short8*)(Whh + (size_t)(128 + jt + l15) * 128 + col);
        un[kf] = *(const short8*)(Whh + (size_t)(256 + jt + l15) * 128 + col);
    }
    __syncthreads();

    floatx4 br  = *(floatx4*)&bhh_lds[j0];
    floatx4 bz  = *(floatx4*)&bhh_lds[128 + j0];
    floatx4 bhn = *(floatx4*)&bhh_lds[256 + j0];
    int lv = lens[n0 + s8];
    float hreg[4] = {0.f, 0.f, 0.f, 0.f};

    // spT group dblk = bx>>1; doc-within-group = (bx&1)*8 + s8
    const ushort_t* sp = spT + (size_t)((bx >> 1) * 32) * 96 * 64
                       + ((bx & 1) * 8 + s8) * 4;
    ushort4 xr_c, xz_c, xn_c, xr_n, xz_n, xn_n;
    {
        int t0 = d ? (T - 1) : 0;
        size_t rb = (size_t)t0 * 96 * 64;
        xr_c = *(const ushort4*)(sp + rb + (size_t)jc * 64);
        xz_c = *(const ushort4*)(sp + rb + (size_t)(32 + jc) * 64);
        xn_c = *(const ushort4*)(sp + rb + (size_t)(64 + jc) * 64);
    }

    for (int ti = 0; ti < T; ++ti) {
        int t = d ? (T - 1 - ti) : ti;
        int cur = ti & 1;
        bool have_next = (ti + 1) < T;
        if (have_next) {
            int tn = d ? (T - 2 - ti) : (ti + 1);
            size_t rb = (size_t)tn * 96 * 64;
            xr_n = *(const ushort4*)(sp + rb + (size_t)jc * 64);
            xz_n = *(const ushort4*)(sp + rb + (size_t)(32 + jc) * 64);
            xn_n = *(const ushort4*)(sp + rb + (size_t)(64 + jc) * 64);
        }
        floatx4 ar = br, az = bz, ahn = bhn;
        #pragma unroll
        for (int kf = 0; kf < 4; ++kf) {
            short8 hb = *(const short8*)&h_buf[cur][X8(kf * 4 + l4, s8)];
            ar  = MFMA16(ur[kf], hb, ar);
            az  = MFMA16(uz[kf], hb, az);
            ahn = MFMA16(un[kf], hb, ahn);
        }
        float xr[4] = {bf2f(xr_c.x), bf2f(xr_c.y), bf2f(xr_c.z), bf2f(xr_c.w)};
        float xz[4] = {bf2f(xz_c.x), bf2f(xz_c.y), bf2f(xz_c.z), bf2f(xz_c.w)};
        float xn[4] = {bf2f(xn_c.x), bf2f(xn_c.y), bf2f(xn_c.z), bf2f(xn_c.w)};
        bool valid = t < lv;
        float hnew[4];
        #pragma unroll
        for (int i = 0; i < 4; ++i) {
            float r  = sig2(xr[i] + ar[i]);
            float z  = sig2(xz[i] + az[i]);
            float nn = tanh2(xn[i] + r * ahn[i]);
            hnew[i] = valid ? (nn + z * (hreg[i] - nn)) : hreg[i];
            hreg[i] = hnew[i];
        }
        if (sv) {
            uint2 h2, o2;
            h2.x = packbf(hnew[0], hnew[1]);
            h2.y = packbf(hnew[2], hnew[3]);
            o2.x = valid ? h2.x : 0u;
            o2.y = valid ? h2.y : 0u;
            *(uint2*)&h_buf[cur ^ 1][X8(j0 >> 3, s8) + (j0 & 7)] = h2;
            *(uint2*)(out + ((size_t)(n0 + s8) * T + t) * 256 + d * 128 + j0) = o2;
        }
        if (have_next) { xr_c = xr_n; xz_c = xz_n; xn_c = xn_n; }
        bar_lds();
    }
}

// ---------------------------------------------------------------------------
// Word attention fused (proj W,b pre-scaled by 2·log2e). 4-acc epilogue.
// ---------------------------------------------------------------------------
__global__ __launch_bounds__(256) void word_attn_kernel(const ushort_t* __restrict__ wout,
                                                        const ushort_t* __restrict__ W,
                                                        const ushort_t* __restrict__ bias,
                                                        const ushort_t* __restrict__ ctx,
                                                        const int* __restrict__ dmax,
                                                        ushort_t* __restrict__ sent) {
    __shared__ ushort_t tile[64 * SP];
    __shared__ float bc[256];
    __shared__ float sc_lds[64];
    __shared__ float p_lds[64];
    int tid = threadIdx.x, g = blockIdx.x;
    for (int idx = tid; idx < 2048; idx += 256) {
        int row = idx >> 5, k0 = (idx & 31) * 8;
        *(uint4*)&tile[row * SP + k0] = *(const uint4*)(wout + ((size_t)g * 64 + row) * 256 + k0);
    }
    if (tid < 128) bc[tid] = bf2f(bias[tid]);
    else bc[tid] = bf2f(ctx[tid - 128]);
    __syncthreads();
    int lane = tid & 63, wave = tid >> 6;
    int l15 = lane & 15, l4 = (lane >> 4) & 3;
    short8 a[8];
    #pragma unroll
    for (int kf = 0; kf < 8; ++kf)
        a[kf] = *(const short8*)&tile[(wave * 16 + l15) * SP + kf * 32 + l4 * 8];
    floatx4 acc[8];
    #pragma unroll
    for (int nt = 0; nt < 8; ++nt) {
        floatx4 c = {0.f, 0.f, 0.f, 0.f};
        #pragma unroll
        for (int kf = 0; kf < 8; ++kf) {
            short8 b = *(const short8*)(W + (size_t)(nt * 16 + l15) * 256 + kf * 32 + l4 * 8);
            c = MFMA16(a[kf], b, c);
        }
        acc[nt] = c;
    }
    float s[4] = {0.f, 0.f, 0.f, 0.f};
    #pragma unroll
    for (int nt = 0; nt < 8; ++nt) {
        float bv = bc[nt * 16 + l15], cv = bc[128 + nt * 16 + l15];
        #pragma unroll
        for (int i = 0; i < 4; ++i)
            s[i] += tanh2(acc[nt][i] + bv) * cv;
    }
    #pragma unroll
    for (int i = 0; i < 4; ++i) {
        s[i] += __shfl_xor(s[i], 1);
        s[i] += __shfl_xor(s[i], 2);
        s[i] += __shfl_xor(s[i], 4);
        s[i] += __shfl_xor(s[i], 8);
    }
    if (l15 == 0) {
        #pragma unroll
        for (int i = 0; i < 4; ++i) sc_lds[wave * 16 + l4 * 4 + i] = s[i];
    }
    __syncthreads();
    if (tid < 64) {
        int ml = dmax[tid & 31];
        for (int off = 32; off; off >>= 1) ml = max(ml, __shfl_xor(ml, off));
        bool v = tid < ml;
        float sc = v ? sc_lds[tid] : -1e30f;
        float mx = sc;
        for (int off = 32; off; off >>= 1) mx = fmaxf(mx, __shfl_xor(mx, off));
        float e = v ? __expf(sc - mx) : 0.f;
        float sum = e;
        for (int off = 32; off; off >>= 1) sum += __shfl_xor(sum, off);
        p_lds[tid] = e * frcp(fmaxf(sum, 1e-30f));
    }
    __syncthreads();
    float a0 = 0.f, a1 = 0.f, a2 = 0.f, a3 = 0.f;
    for (int t = 0; t < 64; t += 4) {
        a0 += p_lds[t]     * bf2f(tile[t * SP + tid]);
        a1 += p_lds[t + 1] * bf2f(tile[(t + 1) * SP + tid]);
        a2 += p_lds[t + 2] * bf2f(tile[(t + 2) * SP + tid]);
        a3 += p_lds[t + 3] * bf2f(tile[(t + 3) * SP + tid]);
    }
    sent[(size_t)g * 256 + tid] = f2bf((a0 + a1) + (a2 + a3));
}

// ---------------------------------------------------------------------------
// Sentence attention + FC fused (proj pre-scaled; FC unscaled).
// ---------------------------------------------------------------------------
__global__ __launch_bounds__(256) void sent_attn_fc_kernel(const ushort_t* __restrict__ sout,
                                                           const ushort_t* __restrict__ W,
                                                           const ushort_t* __restrict__ bias,
                                                           const ushort_t* __restrict__ ctx,
                                                           const ushort_t* __restrict__ fcW,
                                                           const ushort_t* __restrict__ fcb,
                                                           const int* __restrict__ slens,
                                                           const int* __restrict__ flagp,
                                                           void* __restrict__ outp) {
    __shared__ ushort_t tile[32 * SP];
    __shared__ float bc[256];
    __shared__ float sc_lds[32];
    __shared__ float p_lds[32];
    __shared__ float dv[256];
    int tid = threadIdx.x, g = blockIdx.x;
    for (int idx = tid; idx < 1024; idx += 256) {
        int row = idx >> 5, k0 = (idx & 31) * 8;
        *(uint4*)&tile[row * SP + k0] = *(const uint4*)(sout + ((size_t)g * 32 + row) * 256 + k0);
    }
    if (tid < 128) bc[tid] = bf2f(bias[tid]);
    else bc[tid] = bf2f(ctx[tid - 128]);
    __syncthreads();
    int lane = tid & 63, wave = tid >> 6;
    int l15 = lane & 15, l4 = (lane >> 4) & 3;
    if (wave < 2) {
        short8 a[8];
        #pragma unroll
        for (int kf = 0; kf < 8; ++kf)
            a[kf] = *(const short8*)&tile[(wave * 16 + l15) * SP + kf * 32 + l4 * 8];
        floatx4 acc[8];
        #pragma unroll
        for (int nt = 0; nt < 8; ++nt) {
            floatx4 c = {0.f, 0.f, 0.f, 0.f};
            #pragma unroll
            for (int kf = 0; kf < 8; ++kf) {
                short8 b = *(const short8*)(W + (size_t)(nt * 16 + l15) * 256 + kf * 32 + l4 * 8);
                c = MFMA16(a[kf], b, c);
            }
            acc[nt] = c;
        }
        float s[4] = {0.f, 0.f, 0.f, 0.f};
        #pragma unroll
        for (int nt = 0; nt < 8; ++nt) {
            float bv = bc[nt * 16 + l15], cv = bc[128 + nt * 16 + l15];
            #pragma unroll
            for (int i = 0; i < 4; ++i)
                s[i] += tanh2(acc[nt][i] + bv) * cv;
        }
        #pragma unroll
        for (int i = 0; i < 4; ++i) {
            s[i] += __shfl_xor(s[i], 1);
            s[i] += __shfl_xor(s[i], 2);
            s[i] += __shfl_xor(s[i], 4);
            s[i] += __shfl_xor(s[i], 8);
        }
        if (l15 == 0) {
            #pragma unroll
            for (int i = 0; i < 4; ++i) sc_lds[wave * 16 + l4 * 4 + i] = s[i];
        }
    }
    __syncthreads();
    if (tid < 32) {
        int ml = slens[tid];
        for (int off = 16; off; off >>= 1) ml = max(ml, __shfl_xor(ml, off, 32));
        bool v = tid < ml;
        float sc = v ? sc_lds[tid] : -1e30f;
        float mx = sc;
        for (int off = 16; off; off >>= 1) mx = fmaxf(mx, __shfl_xor(mx, off, 32));
        float e = v ? __expf(sc - mx) : 0.f;
        float sum = e;
        for (int off = 16; off; off >>= 1) sum += __shfl_xor(sum, off, 32);
        p_lds[tid] = e * frcp(fmaxf(sum, 1e-30f));
    }
    __syncthreads();
    float acc2 = 0.f;
    for (int t = 0; t < 32; ++t) acc2 += p_lds[t] * bf2f(tile[t * SP + tid]);
    dv[tid] = acc2;
    __syncthreads();
    int c = tid >> 5, q0 = (tid & 31) * 8;
    float partial = 0.f;
    #pragma unroll
    for (int q = 0; q < 8; ++q)
        partial += dv[q0 + q] * bf2f(fcW[(size_t)c * 256 + q0 + q]);
    for (int off = 16; off; off >>= 1) partial += __shfl_xor(partial, off, 32);
    if ((tid & 31) == 0) {
        float v = partial + bf2f(fcb[c]);
        if (*flagp) ((float*)outp)[g * 8 + c] = v;
        else        ((ushort_t*)outp)[g * 8 + c] = f2bf(v);
    }
}

// ---------------------------------------------------------------------------
extern "C" void kernel_launch(void* const* d_in, const int* in_sizes, int n_in,
                              void* d_out, int out_size, void* d_ws, size_t ws_size,
                              hipStream_t stream) {
    const int* x = (const int*)d_in[0];
    char* ws = (char*)d_ws;

    const size_t O_CONV = 0;            // canonical bf16 inputs (~14 MB)
    const size_t O_WOUT = 14680064;     // [65536,256] bf16  33.55 MB
    const size_t O_SENT = 48234496;     // [1024,256] bf16
    const size_t O_SOUT = 48758784;     // [1024,256] bf16
    const size_t O_SPTF = 49283072;     // spT fwd 1.5MB
    const size_t O_SPTB = 50855936;     // spT bwd
    const size_t O_LENS = 52428800;
    const size_t O_SLEN = 52432896;
    const size_t O_DMAX = 52433024;
    const size_t O_FLAG = 52433152;

    ushort_t* conv = (ushort_t*)(ws + O_CONV);
    ushort_t* wout = (ushort_t*)(ws + O_WOUT);
    ushort_t* sent = (ushort_t*)(ws + O_SENT);
    ushort_t* sout = (ushort_t*)(ws + O_SOUT);
    ushort_t* sptf = (ushort_t*)(ws + O_SPTF);
    ushort_t* sptb = (ushort_t*)(ws + O_SPTB);
    int* wlens = (int*)(ws + O_LENS);
    int* slens = (int*)(ws + O_SLEN);
    int* dmax  = (int*)(ws + O_DMAX);
    int* flag  = (int*)(ws + O_FLAG);

    static const int kMode[25]   = {0, 1,1,1,1, 1,1,1,1, 1,1,1,1, 1,1,1,1, 2,2,0, 2,2,0, 0,0};
    static const int kRowdiv[25] = {1, 128,128,1,1, 128,128,1,1, 256,128,1,1, 256,128,1,1,
                                    1,1,1, 1,1,1, 1,1};

    ConvArgs ca;
    ushort_t* cw[25];
    int off = 0, blk = 0;
    for (int i = 1; i <= 25; ++i) {
        int j = i - 1;
        int cnt = in_sizes[i];
        ca.src[j] = d_in[i];
        ca.dstoff[j] = off;
        ca.count[j] = cnt;
        ca.cumblk[j] = blk;
        ca.mode[j] = kMode[j];
        ca.rowdiv[j] = kRowdiv[j];
        cw[j] = conv + off;
        off += cnt;
        blk += (cnt + 2047) / 2048;
    }
    ca.cumblk[25] = blk;

    // 1) canonicalize + lens + dtype flag (merged; lens = 32 extra blocks)
    convert_kernel<<<blk + 32, 256, 0, stream>>>(ca, conv, x, wlens, slens, dmax, flag);
    // 2) word BiGRU (8 seqs/block, 256 blocks -> all CUs)
    word_gru_kernel<<<dim3(128, 2), 512, 0, stream>>>(
        x, cw[0],
        cw[1], cw[2], cw[3], cw[4],
        cw[5], cw[6], cw[7], cw[8],
        wlens, wout);
    // --- MEASUREMENT: tail chain launched TWICE (idempotent). Δ vs round-6
    // total (277.9) = true cost of {wattn, spt, sgru, sattn} incl. dispatch.
    for (int rep = 0; rep < 2; ++rep) {
        // 3) word attention -> sent
        word_attn_kernel<<<1024, 256, 0, stream>>>(wout, cw[17], cw[18], cw[19], dmax, sent);
        // 4) sentence xp -> spT (192 blocks, wide)
        spt_gemm_kernel<<<dim3(16, 12), 256, 0, stream>>>(sent, cw[9], cw[11], sptf,
                                                          cw[13], cw[15], sptb);
        // 5) sentence BiGRU (8 docs/block, 8 blocks)
        sent_gru_kernel<<<dim3(4, 2), 512, 0, stream>>>(
            sptf, sptb, cw[10], cw[14], cw[12], cw[16], slens, sout);
        // 6) sentence attention + FC -> d_out
        sent_attn_fc_kernel<<<32, 256, 0, stream>>>(sout, cw[20], cw[21], cw[22],
                                                    cw[23], cw[24], slens, flag, d_out);
    }
    (void)n_in; (void)out_size; (void)ws_size;
}

// Round 9
// 288.501 us; speedup vs baseline: 1.5203x; 1.2398x over previous
//
#include <hip/hip_runtime.h>
#include <hip/hip_bf16.h>

typedef unsigned short ushort_t;
typedef __attribute__((ext_vector_type(4))) float floatx4;
typedef __attribute__((ext_vector_type(8))) short short8;

#define L2E 1.4426950408889634f

__device__ __forceinline__ float bf2f(ushort_t u) {
    union { unsigned int i; float f; } v; v.i = ((unsigned int)u) << 16; return v.f;
}
__device__ __forceinline__ ushort_t f2bf(float f) {
    union { float f; unsigned int i; } v; v.f = f;
    unsigned int i = v.i;
    i += 0x7fffu + ((i >> 16) & 1u);            // RNE
    return (ushort_t)(i >> 16);
}
__device__ __forceinline__ float fexp2(float x) {
#if __has_builtin(__builtin_amdgcn_exp2f)
    return __builtin_amdgcn_exp2f(x);
#else
    return __expf(x * 0.6931471805599453f);
#endif
}
__device__ __forceinline__ float frcp(float x) {
#if __has_builtin(__builtin_amdgcn_rcpf)
    return __builtin_amdgcn_rcpf(x);
#else
    return 1.f / x;
#endif
}
// σ(x) with pre-scaled input a = −log2e·x ; tanh(x) with y = 2·log2e·x.
__device__ __forceinline__ float sig2(float a)  { return frcp(1.f + fexp2(a)); }
__device__ __forceinline__ float tanh2(float y) { return 1.f - 2.f * frcp(1.f + fexp2(y)); }

__device__ __forceinline__ unsigned int packbf(float a, float b) {
    float2 t; t.x = a; t.y = b;
    __hip_bfloat162 h = __float22bfloat162_rn(t);
    union { __hip_bfloat162 h; unsigned int u; } v; v.h = h; return v.u;
}

__device__ __forceinline__ floatx4 MFMA16(short8 a, short8 b, floatx4 c) {
    return __builtin_amdgcn_mfma_f32_16x16x32_bf16(a, b, c, 0, 0, 0);
}

// LDS-only barrier: lgkmcnt(0) only (vmcnt/expcnt maxed) + raw s_barrier.
__device__ __forceinline__ void bar_lds() {
    __builtin_amdgcn_s_waitcnt(0xc07f);
    __builtin_amdgcn_s_barrier();
}

// 8-seq swizzled LDS index: [chunk c(16)][seq m(8)][8 elems]
#define X8(c, m) ((((c) * 8) + ((m) ^ ((c) & 7))) * 8)
#define SP 264

// ---------------------------------------------------------------------------
// K0: canonicalize inputs -> bf16 (folding activation scales into weights),
// PLUS (merged) the lens/dtype work as 32 appended blocks.
// ---------------------------------------------------------------------------
struct ConvArgs {
    const void* src[25];
    int dstoff[25];
    int count[25];
    int cumblk[26];
    int mode[25];     // 0 none, 1 GRU (row<256 ? -L2E : 2L2E), 2 all 2L2E
    int rowdiv[25];
};

__global__ __launch_bounds__(256) void convert_kernel(ConvArgs a, ushort_t* __restrict__ dst,
                                                      const int* __restrict__ x,
                                                      int* wlens, int* slens, int* dmax,
                                                      int* flagp) {
    __shared__ int flag_lds;
    int tid = threadIdx.x, b = blockIdx.x;
    if (tid < 64) {
        unsigned int v = ((const unsigned int*)a.src[0])[tid];
        unsigned long long mball = __ballot(((v >> 7) & 0xFFu) > 0x7Bu);
        if (tid == 0) flag_lds = (__popcll(mball) > 8) ? 1 : 0;
    }
    __syncthreads();
    int flagv = flag_lds;
    int cblk = a.cumblk[25];

    if (b >= cblk) {
        int bb = b - cblk;
        if (bb == 0 && tid == 0) *flagp = flagv;
        if (tid < 64) {
            int s = tid;
            int last = 0;
            if (s < 32) {
                const int* tok = x + (bb * 32 + s) * 64;
                for (int t = 0; t < 64; t += 4) {
                    int4 v = *(const int4*)(tok + t);
                    if (v.x) last = t + 1;
                    if (v.y) last = t + 2;
                    if (v.z) last = t + 3;
                    if (v.w) last = t + 4;
                }
                wlens[bb * 32 + s] = last ? last : 1;
            }
            int len = (s < 32) ? (last ? last : 1) : 0;
            int lm = len;
            for (int off = 32; off; off >>= 1) lm = max(lm, __shfl_xor(lm, off));
            unsigned long long mask = __ballot(s < 32 && last > 0);
            if (s == 0) {
                slens[bb] = mask ? (63 - (int)__clzll(mask) + 1) : 1;
                dmax[bb] = lm;
            }
        }
        return;
    }

    int lo = 0, hi = 24;
    while (lo < hi) { int mid = (lo + hi + 1) >> 1; if (a.cumblk[mid] <= b) lo = mid; else hi = mid - 1; }
    int j = lo;
    int base = (b - a.cumblk[j]) * 2048 + tid * 8;
    if (base >= a.count[j]) return;
    ushort_t* out = dst + a.dstoff[j] + base;
    int m = a.mode[j], rd = a.rowdiv[j];
    float f[8];
    if (flagv) {
        const float* s = (const float*)a.src[j] + base;
        float4 v0 = *(const float4*)s;
        float4 v1 = *(const float4*)(s + 4);
        f[0] = v0.x; f[1] = v0.y; f[2] = v0.z; f[3] = v0.w;
        f[4] = v1.x; f[5] = v1.y; f[6] = v1.z; f[7] = v1.w;
    } else {
        const ushort_t* s = (const ushort_t*)a.src[j] + base;
        uint4 v = *(const uint4*)s;
        const ushort_t* u = (const ushort_t*)&v;
        #pragma unroll
        for (int e = 0; e < 8; ++e) f[e] = bf2f(u[e]);
    }
    union { ushort_t u[8]; uint4 v; } o;
    #pragma unroll
    for (int e = 0; e < 8; ++e) {
        float sc = 1.f;
        if (m == 2) sc = 2.f * L2E;
        else if (m == 1) sc = ((base + e) / rd < 256) ? -L2E : 2.f * L2E;
        o.u[e] = f2bf(f[e] * sc);
    }
    *(uint4*)out = o.v;
}

// ---------------------------------------------------------------------------
// Word-level BiGRU v5 (round-1 form — verified local optimum; do not touch):
// 8 seqs/block, grid (128,2) = 256 blocks. 512 thr / 8 waves.
// ---------------------------------------------------------------------------
__global__ __launch_bounds__(512, 2) void word_gru_kernel(
        const int* __restrict__ x, const ushort_t* __restrict__ emb,
        const ushort_t* __restrict__ Wih_f, const ushort_t* __restrict__ Whh_f,
        const ushort_t* __restrict__ bih_f, const ushort_t* __restrict__ bhh_f,
        const ushort_t* __restrict__ Wih_b, const ushort_t* __restrict__ Whh_b,
        const ushort_t* __restrict__ bih_b, const ushort_t* __restrict__ bhh_b,
        const int* __restrict__ lens, ushort_t* __restrict__ out) {
    const int T = 64;
    __shared__ ushort_t h_buf[2][1024];      // [chunk16][seq8][8] swizzled
    __shared__ float bsum_lds[256];
    __shared__ float bihn_lds[128];
    __shared__ float bhhn_lds[128];
    __shared__ int tok_lds[512];             // [t][s(8)]

    int tid = threadIdx.x;
    int d = blockIdx.y;
    int n0 = blockIdx.x * 8;
    const ushort_t* Wih = d ? Wih_b : Wih_f;
    const ushort_t* Whh = d ? Whh_b : Whh_f;
    const ushort_t* bih = d ? bih_b : bih_f;
    const ushort_t* bhh = d ? bhh_b : bhh_f;
    int lane = tid & 63, wave = tid >> 6;
    int l15 = lane & 15, l4 = (lane >> 4) & 3;
    int s8 = l15 & 7;                        // clamped seq index
    bool sv = l15 < 8;                       // this lane's col is valid
    int jt = wave * 16;
    int j0 = jt + l4 * 4;

    {
        int t = tid >> 3, s = tid & 7;
        tok_lds[tid] = x[(n0 + s) * 64 + t];
    }
    if (tid < 256) bsum_lds[tid] = bf2f(bih[tid]) + bf2f(bhh[tid]);
    else if (tid < 384) {
        bihn_lds[tid - 256] = bf2f(bih[tid]);
        bhhn_lds[tid - 256] = bf2f(bhh[tid]);
    }
    if (tid < 256) { uint2 z = {0u, 0u}; *(uint2*)&h_buf[0][tid * 4] = z; }

    short8 wr[4], wz[4], wn[4], ur[4], uz[4], un[4];
    #pragma unroll
    for (int kf = 0; kf < 4; ++kf) {
        int col = kf * 32 + l4 * 8;
        wr[kf] = *(const short8*)(Wih + (size_t)(jt + l15) * 128 + col);
        wz[kf] = *(const short8*)(Wih + (size_t)(128 + jt + l15) * 128 + col);
        wn[kf] = *(const short8*)(Wih + (size_t)(256 + jt + l15) * 128 + col);
        ur[kf] = *(const short8*)(Whh + (size_t)(jt + l15) * 128 + col);
        uz[kf] = *(const short8*)(Whh + (size_t)(128 + jt + l15) * 128 + col);
        un[kf] = *(const short8*)(Whh + (size_t)(256 + jt + l15) * 128 + col);
    }
    __syncthreads();

    floatx4 br  = *(floatx4*)&bsum_lds[j0];
    floatx4 bz  = *(floatx4*)&bsum_lds[128 + j0];
    floatx4 bxn = *(floatx4*)&bihn_lds[j0];
    floatx4 bhn = *(floatx4*)&bhhn_lds[j0];
    int lv = lens[n0 + s8];
    float hreg[4] = {0.f, 0.f, 0.f, 0.f};

    short8 xc[4], xn_[4];
    {
        int t0 = d ? (T - 1) : 0;
        size_t rb = (size_t)tok_lds[t0 * 8 + s8] * 128 + l4 * 8;
        #pragma unroll
        for (int kf = 0; kf < 4; ++kf)
            xc[kf] = *(const short8*)(emb + rb + kf * 32);
    }

    for (int ti = 0; ti < T; ++ti) {
        int t = d ? (T - 1 - ti) : ti;
        bool have_next = (ti + 1) < T;
        if (have_next) {
            int tn = d ? (T - 2 - ti) : (ti + 1);
            size_t rb = (size_t)tok_lds[tn * 8 + s8] * 128 + l4 * 8;
            #pragma unroll
            for (int kf = 0; kf < 4; ++kf)
                xn_[kf] = *(const short8*)(emb + rb + kf * 32);
        }
        short8 hb[4];
        #pragma unroll
        for (int kf = 0; kf < 4; ++kf)
            hb[kf] = *(const short8*)&h_buf[ti & 1][X8(kf * 4 + l4, s8)];
        floatx4 arx = br, azx = bz, axn = bxn;
        floatx4 arh = {0.f, 0.f, 0.f, 0.f}, azh = {0.f, 0.f, 0.f, 0.f}, ahn = bhn;
        #pragma unroll
        for (int kf = 0; kf < 4; ++kf) {
            arx = MFMA16(wr[kf], xc[kf], arx);
            azx = MFMA16(wz[kf], xc[kf], azx);
            axn = MFMA16(wn[kf], xc[kf], axn);
        }
        #pragma unroll
        for (int kf = 0; kf < 4; ++kf) {
            arh = MFMA16(ur[kf], hb[kf], arh);
            azh = MFMA16(uz[kf], hb[kf], azh);
            ahn = MFMA16(un[kf], hb[kf], ahn);
        }
        bool valid = t < lv;
        float hnew[4];
        #pragma unroll
        for (int i = 0; i < 4; ++i) {
            float r  = sig2(arx[i] + arh[i]);
            float z  = sig2(azx[i] + azh[i]);
            float nn = tanh2(axn[i] + r * ahn[i]);
            hnew[i] = valid ? (nn + z * (hreg[i] - nn)) : hreg[i];
            hreg[i] = hnew[i];
        }
        if (sv) {
            uint2 h2, o2;
            h2.x = packbf(hnew[0], hnew[1]);
            h2.y = packbf(hnew[2], hnew[3]);
            o2.x = valid ? h2.x : 0u;
            o2.y = valid ? h2.y : 0u;
            *(uint2*)&h_buf[(ti & 1) ^ 1][X8(j0 >> 3, s8) + (j0 & 7)] = h2;
            *(uint2*)(out + ((size_t)(n0 + s8) * T + t) * 256 + d * 128 + j0) = o2;
        }
        if (have_next) {
            #pragma unroll
            for (int kf = 0; kf < 4; ++kf) xc[kf] = xn_[kf];
        }
        bar_lds();
    }
}

// ---------------------------------------------------------------------------
// Sentence xp GEMM -> transposed layout spT (weights pre-scaled at convert).
// 192 blocks — keep wide; 8-block fusion cost +56 µs (round-5 lesson).
// ---------------------------------------------------------------------------
__global__ __launch_bounds__(256) void spt_gemm_kernel(const ushort_t* __restrict__ A,
                                                       const ushort_t* __restrict__ Bf_,
                                                       const ushort_t* __restrict__ biasf,
                                                       ushort_t* __restrict__ Tf_,
                                                       const ushort_t* __restrict__ Bb_,
                                                       const ushort_t* __restrict__ biasb,
                                                       ushort_t* __restrict__ Tb_) {
    __shared__ ushort_t As[64 * 256];
    __shared__ ushort_t Bs[64 * 256];
    const int K = 256;
    int tid = threadIdx.x;
    int by = blockIdx.y;
    bool sb = by >= 6;
    int n0 = (sb ? by - 6 : by) * 64;
    const ushort_t* B = sb ? Bb_ : Bf_;
    const ushort_t* bias = sb ? biasb : biasf;
    ushort_t* Tp = sb ? Tb_ : Tf_;
    int m0 = blockIdx.x * 64;
    for (int idx = tid; idx < 2048; idx += 256) {
        int m = idx & 63, c = idx >> 6;
        *(uint4*)&As[(c * 64 + m) * 8] = *(const uint4*)(A + (size_t)(m0 + m) * K + c * 8);
    }
    for (int idx = tid; idx < 2048; idx += 256) {
        int n = idx & 63, c = idx >> 6;
        *(uint4*)&Bs[(c * 64 + n) * 8] = *(const uint4*)(B + (size_t)(n0 + n) * K + c * 8);
    }
    __syncthreads();
    int lane = tid & 63, wave = tid >> 6;
    int wm = (wave & 1) * 32, wn = (wave >> 1) * 32;
    int l15 = lane & 15, l4 = lane >> 4;
    floatx4 acc[2][2] = {};
    for (int kf = 0; kf < 8; ++kf) {
        int c = kf * 4 + l4;
        short8 a0 = *(const short8*)&As[(c * 64 + wm + l15) * 8];
        short8 a1 = *(const short8*)&As[(c * 64 + wm + 16 + l15) * 8];
        short8 b0 = *(const short8*)&Bs[(c * 64 + wn + l15) * 8];
        short8 b1 = *(const short8*)&Bs[(c * 64 + wn + 16 + l15) * 8];
        acc[0][0] = MFMA16(a0, b0, acc[0][0]);
        acc[0][1] = MFMA16(a0, b1, acc[0][1]);
        acc[1][0] = MFMA16(a1, b0, acc[1][0]);
        acc[1][1] = MFMA16(a1, b1, acc[1][1]);
    }
    for (int nt = 0; nt < 2; ++nt) {
        int n = n0 + wn + nt * 16 + l15;
        float bv = bf2f(bias[n]);
        int jc = n >> 2, ji = n & 3;
        for (int mt = 0; mt < 2; ++mt) {
            int mbase = m0 + wm + mt * 16 + l4 * 4;
            #pragma unroll
            for (int i = 0; i < 4; ++i) {
                int m = mbase + i;
                int doc = m >> 5, t = m & 31;
                size_t dst = ((size_t)((doc >> 4) * 32 + t) * 96 + jc) * 64
                           + (doc & 15) * 4 + ji;
                Tp[dst] = f2bf(acc[mt][nt][i] + bv);
            }
        }
    }
}

// ---------------------------------------------------------------------------
// Sentence-level BiGRU: 8 docs/block, grid (4,2) = 8 blocks. (round-1 form)
// ---------------------------------------------------------------------------
__global__ __launch_bounds__(512, 2) void sent_gru_kernel(
        const ushort_t* __restrict__ spT_f, const ushort_t* __restrict__ spT_b,
        const ushort_t* __restrict__ Whh_f, const ushort_t* __restrict__ Whh_b,
        const ushort_t* __restrict__ bhh_f, const ushort_t* __restrict__ bhh_b,
        const int* __restrict__ lens, ushort_t* __restrict__ out) {
    const int T = 32;
    __shared__ ushort_t h_buf[2][1024];
    __shared__ float bhh_lds[384];

    int tid = threadIdx.x;
    int d = blockIdx.y;
    int bx = blockIdx.x;
    int n0 = bx * 8;
    const ushort_t* spT = d ? spT_b : spT_f;
    const ushort_t* Whh = d ? Whh_b : Whh_f;
    const ushort_t* bhh = d ? bhh_b : bhh_f;
    int lane = tid & 63, wave = tid >> 6;
    int l15 = lane & 15, l4 = (lane >> 4) & 3;
    int s8 = l15 & 7;
    bool sv = l15 < 8;
    int jt = wave * 16;
    int j0 = jt + l4 * 4;
    int jc = j0 >> 2;

    if (tid < 384) bhh_lds[tid] = bf2f(bhh[tid]);
    if (tid < 256) { uint2 z = {0u, 0u}; *(uint2*)&h_buf[0][tid * 4] = z; }

    short8 ur[4], uz[4], un[4];
    #pragma unroll
    for (int kf = 0; kf < 4; ++kf) {
        int col = kf * 32 + l4 * 8;
        ur[kf] = *(const short8*)(Whh + (size_t)(jt + l15) * 128 + col);
        uz[kf] = *(const short8*)(Whh + (size_t)(128 + jt + l15) * 128 + col);
        un[kf] = *(const short8*)(Whh + (size_t)(256 + jt + l15) * 128 + col);
    }
    __syncthreads();

    floatx4 br  = *(floatx4*)&bhh_lds[j0];
    floatx4 bz  = *(floatx4*)&bhh_lds[128 + j0];
    floatx4 bhn = *(floatx4*)&bhh_lds[256 + j0];
    int lv = lens[n0 + s8];
    float hreg[4] = {0.f, 0.f, 0.f, 0.f};

    // spT group dblk = bx>>1; doc-within-group = (bx&1)*8 + s8
    const ushort_t* sp = spT + (size_t)((bx >> 1) * 32) * 96 * 64
                       + ((bx & 1) * 8 + s8) * 4;
    ushort4 xr_c, xz_c, xn_c, xr_n, xz_n, xn_n;
    {
        int t0 = d ? (T - 1) : 0;
        size_t rb = (size_t)t0 * 96 * 64;
        xr_c = *(const ushort4*)(sp + rb + (size_t)jc * 64);
        xz_c = *(const ushort4*)(sp + rb + (size_t)(32 + jc) * 64);
        xn_c = *(const ushort4*)(sp + rb + (size_t)(64 + jc) * 64);
    }

    for (int ti = 0; ti < T; ++ti) {
        int t = d ? (T - 1 - ti) : ti;
        int cur = ti & 1;
        bool have_next = (ti + 1) < T;
        if (have_next) {
            int tn = d ? (T - 2 - ti) : (ti + 1);
            size_t rb = (size_t)tn * 96 * 64;
            xr_n = *(const ushort4*)(sp + rb + (size_t)jc * 64);
            xz_n = *(const ushort4*)(sp + rb + (size_t)(32 + jc) * 64);
            xn_n = *(const ushort4*)(sp + rb + (size_t)(64 + jc) * 64);
        }
        floatx4 ar = br, az = bz, ahn = bhn;
        #pragma unroll
        for (int kf = 0; kf < 4; ++kf) {
            short8 hb = *(const short8*)&h_buf[cur][X8(kf * 4 + l4, s8)];
            ar  = MFMA16(ur[kf], hb, ar);
            az  = MFMA16(uz[kf], hb, az);
            ahn = MFMA16(un[kf], hb, ahn);
        }
        float xr[4] = {bf2f(xr_c.x), bf2f(xr_c.y), bf2f(xr_c.z), bf2f(xr_c.w)};
        float xz[4] = {bf2f(xz_c.x), bf2f(xz_c.y), bf2f(xz_c.z), bf2f(xz_c.w)};
        float xn[4] = {bf2f(xn_c.x), bf2f(xn_c.y), bf2f(xn_c.z), bf2f(xn_c.w)};
        bool valid = t < lv;
        float hnew[4];
        #pragma unroll
        for (int i = 0; i < 4; ++i) {
            float r  = sig2(xr[i] + ar[i]);
            float z  = sig2(xz[i] + az[i]);
            float nn = tanh2(xn[i] + r * ahn[i]);
            hnew[i] = valid ? (nn + z * (hreg[i] - nn)) : hreg[i];
            hreg[i] = hnew[i];
        }
        if (sv) {
            uint2 h2, o2;
            h2.x = packbf(hnew[0], hnew[1]);
            h2.y = packbf(hnew[2], hnew[3]);
            o2.x = valid ? h2.x : 0u;
            o2.y = valid ? h2.y : 0u;
            *(uint2*)&h_buf[cur ^ 1][X8(j0 >> 3, s8) + (j0 & 7)] = h2;
            *(uint2*)(out + ((size_t)(n0 + s8) * T + t) * 256 + d * 128 + j0) = o2;
        }
        if (have_next) { xr_c = xr_n; xz_c = xz_n; xn_c = xn_n; }
        bar_lds();
    }
}

// ---------------------------------------------------------------------------
// Word attention fused (proj W,b pre-scaled by 2·log2e). 4-acc epilogue.
// ---------------------------------------------------------------------------
__global__ __launch_bounds__(256) void word_attn_kernel(const ushort_t* __restrict__ wout,
                                                        const ushort_t* __restrict__ W,
                                                        const ushort_t* __restrict__ bias,
                                                        const ushort_t* __restrict__ ctx,
                                                        const int* __restrict__ dmax,
                                                        ushort_t* __restrict__ sent) {
    __shared__ ushort_t tile[64 * SP];
    __shared__ float bc[256];
    __shared__ float sc_lds[64];
    __shared__ float p_lds[64];
    int tid = threadIdx.x, g = blockIdx.x;
    for (int idx = tid; idx < 2048; idx += 256) {
        int row = idx >> 5, k0 = (idx & 31) * 8;
        *(uint4*)&tile[row * SP + k0] = *(const uint4*)(wout + ((size_t)g * 64 + row) * 256 + k0);
    }
    if (tid < 128) bc[tid] = bf2f(bias[tid]);
    else bc[tid] = bf2f(ctx[tid - 128]);
    __syncthreads();
    int lane = tid & 63, wave = tid >> 6;
    int l15 = lane & 15, l4 = (lane >> 4) & 3;
    short8 a[8];
    #pragma unroll
    for (int kf = 0; kf < 8; ++kf)
        a[kf] = *(const short8*)&tile[(wave * 16 + l15) * SP + kf * 32 + l4 * 8];
    floatx4 acc[8];
    #pragma unroll
    for (int nt = 0; nt < 8; ++nt) {
        floatx4 c = {0.f, 0.f, 0.f, 0.f};
        #pragma unroll
        for (int kf = 0; kf < 8; ++kf) {
            short8 b = *(const short8*)(W + (size_t)(nt * 16 + l15) * 256 + kf * 32 + l4 * 8);
            c = MFMA16(a[kf], b, c);
        }
        acc[nt] = c;
    }
    float s[4] = {0.f, 0.f, 0.f, 0.f};
    #pragma unroll
    for (int nt = 0; nt < 8; ++nt) {
        float bv = bc[nt * 16 + l15], cv = bc[128 + nt * 16 + l15];
        #pragma unroll
        for (int i = 0; i < 4; ++i)
            s[i] += tanh2(acc[nt][i] + bv) * cv;
    }
    #pragma unroll
    for (int i = 0; i < 4; ++i) {
        s[i] += __shfl_xor(s[i], 1);
        s[i] += __shfl_xor(s[i], 2);
        s[i] += __shfl_xor(s[i], 4);
        s[i] += __shfl_xor(s[i], 8);
    }
    if (l15 == 0) {
        #pragma unroll
        for (int i = 0; i < 4; ++i) sc_lds[wave * 16 + l4 * 4 + i] = s[i];
    }
    __syncthreads();
    if (tid < 64) {
        int ml = dmax[tid & 31];
        for (int off = 32; off; off >>= 1) ml = max(ml, __shfl_xor(ml, off));
        bool v = tid < ml;
        float sc = v ? sc_lds[tid] : -1e30f;
        float mx = sc;
        for (int off = 32; off; off >>= 1) mx = fmaxf(mx, __shfl_xor(mx, off));
        float e = v ? __expf(sc - mx) : 0.f;
        float sum = e;
        for (int off = 32; off; off >>= 1) sum += __shfl_xor(sum, off);
        p_lds[tid] = e * frcp(fmaxf(sum, 1e-30f));
    }
    __syncthreads();
    float a0 = 0.f, a1 = 0.f, a2 = 0.f, a3 = 0.f;
    for (int t = 0; t < 64; t += 4) {
        a0 += p_lds[t]     * bf2f(tile[t * SP + tid]);
        a1 += p_lds[t + 1] * bf2f(tile[(t + 1) * SP + tid]);
        a2 += p_lds[t + 2] * bf2f(tile[(t + 2) * SP + tid]);
        a3 += p_lds[t + 3] * bf2f(tile[(t + 3) * SP + tid]);
    }
    sent[(size_t)g * 256 + tid] = f2bf((a0 + a1) + (a2 + a3));
}

// ---------------------------------------------------------------------------
// Sentence attention + FC fused (proj pre-scaled; FC unscaled).
// ---------------------------------------------------------------------------
__global__ __launch_bounds__(256) void sent_attn_fc_kernel(const ushort_t* __restrict__ sout,
                                                           const ushort_t* __restrict__ W,
                                                           const ushort_t* __restrict__ bias,
                                                           const ushort_t* __restrict__ ctx,
                                                           const ushort_t* __restrict__ fcW,
                                                           const ushort_t* __restrict__ fcb,
                                                           const int* __restrict__ slens,
                                                           const int* __restrict__ flagp,
                                                           void* __restrict__ outp) {
    __shared__ ushort_t tile[32 * SP];
    __shared__ float bc[256];
    __shared__ float sc_lds[32];
    __shared__ float p_lds[32];
    __shared__ float dv[256];
    int tid = threadIdx.x, g = blockIdx.x;
    for (int idx = tid; idx < 1024; idx += 256) {
        int row = idx >> 5, k0 = (idx & 31) * 8;
        *(uint4*)&tile[row * SP + k0] = *(const uint4*)(sout + ((size_t)g * 32 + row) * 256 + k0);
    }
    if (tid < 128) bc[tid] = bf2f(bias[tid]);
    else bc[tid] = bf2f(ctx[tid - 128]);
    __syncthreads();
    int lane = tid & 63, wave = tid >> 6;
    int l15 = lane & 15, l4 = (lane >> 4) & 3;
    if (wave < 2) {
        short8 a[8];
        #pragma unroll
        for (int kf = 0; kf < 8; ++kf)
            a[kf] = *(const short8*)&tile[(wave * 16 + l15) * SP + kf * 32 + l4 * 8];
        floatx4 acc[8];
        #pragma unroll
        for (int nt = 0; nt < 8; ++nt) {
            floatx4 c = {0.f, 0.f, 0.f, 0.f};
            #pragma unroll
            for (int kf = 0; kf < 8; ++kf) {
                short8 b = *(const short8*)(W + (size_t)(nt * 16 + l15) * 256 + kf * 32 + l4 * 8);
                c = MFMA16(a[kf], b, c);
            }
            acc[nt] = c;
        }
        float s[4] = {0.f, 0.f, 0.f, 0.f};
        #pragma unroll
        for (int nt = 0; nt < 8; ++nt) {
            float bv = bc[nt * 16 + l15], cv = bc[128 + nt * 16 + l15];
            #pragma unroll
            for (int i = 0; i < 4; ++i)
                s[i] += tanh2(acc[nt][i] + bv) * cv;
        }
        #pragma unroll
        for (int i = 0; i < 4; ++i) {
            s[i] += __shfl_xor(s[i], 1);
            s[i] += __shfl_xor(s[i], 2);
            s[i] += __shfl_xor(s[i], 4);
            s[i] += __shfl_xor(s[i], 8);
        }
        if (l15 == 0) {
            #pragma unroll
            for (int i = 0; i < 4; ++i) sc_lds[wave * 16 + l4 * 4 + i] = s[i];
        }
    }
    __syncthreads();
    if (tid < 32) {
        int ml = slens[tid];
        for (int off = 16; off; off >>= 1) ml = max(ml, __shfl_xor(ml, off, 32));
        bool v = tid < ml;
        float sc = v ? sc_lds[tid] : -1e30f;
        float mx = sc;
        for (int off = 16; off; off >>= 1) mx = fmaxf(mx, __shfl_xor(mx, off, 32));
        float e = v ? __expf(sc - mx) : 0.f;
        float sum = e;
        for (int off = 16; off; off >>= 1) sum += __shfl_xor(sum, off, 32);
        p_lds[tid] = e * frcp(fmaxf(sum, 1e-30f));
    }
    __syncthreads();
    float acc2 = 0.f;
    for (int t = 0; t < 32; ++t) acc2 += p_lds[t] * bf2f(tile[t * SP + tid]);
    dv[tid] = acc2;
    __syncthreads();
    int c = tid >> 5, q0 = (tid & 31) * 8;
    float partial = 0.f;
    #pragma unroll
    for (int q = 0; q < 8; ++q)
        partial += dv[q0 + q] * bf2f(fcW[(size_t)c * 256 + q0 + q]);
    for (int off = 16; off; off >>= 1) partial += __shfl_xor(partial, off, 32);
    if ((tid & 31) == 0) {
        float v = partial + bf2f(fcb[c]);
        if (*flagp) ((float*)outp)[g * 8 + c] = v;
        else        ((ushort_t*)outp)[g * 8 + c] = f2bf(v);
    }
}

// ---------------------------------------------------------------------------
extern "C" void kernel_launch(void* const* d_in, const int* in_sizes, int n_in,
                              void* d_out, int out_size, void* d_ws, size_t ws_size,
                              hipStream_t stream) {
    const int* x = (const int*)d_in[0];
    char* ws = (char*)d_ws;

    const size_t O_CONV = 0;            // canonical bf16 inputs (~14 MB)
    const size_t O_WOUT = 14680064;     // [65536,256] bf16  33.55 MB
    const size_t O_SENT = 48234496;     // [1024,256] bf16
    const size_t O_SOUT = 48758784;     // [1024,256] bf16
    const size_t O_SPTF = 49283072;     // spT fwd 1.5MB
    const size_t O_SPTB = 50855936;     // spT bwd
    const size_t O_LENS = 52428800;
    const size_t O_SLEN = 52432896;
    const size_t O_DMAX = 52433024;
    const size_t O_FLAG = 52433152;

    ushort_t* conv = (ushort_t*)(ws + O_CONV);
    ushort_t* wout = (ushort_t*)(ws + O_WOUT);
    ushort_t* sent = (ushort_t*)(ws + O_SENT);
    ushort_t* sout = (ushort_t*)(ws + O_SOUT);
    ushort_t* sptf = (ushort_t*)(ws + O_SPTF);
    ushort_t* sptb = (ushort_t*)(ws + O_SPTB);
    int* wlens = (int*)(ws + O_LENS);
    int* slens = (int*)(ws + O_SLEN);
    int* dmax  = (int*)(ws + O_DMAX);
    int* flag  = (int*)(ws + O_FLAG);

    static const int kMode[25]   = {0, 1,1,1,1, 1,1,1,1, 1,1,1,1, 1,1,1,1, 2,2,0, 2,2,0, 0,0};
    static const int kRowdiv[25] = {1, 128,128,1,1, 128,128,1,1, 256,128,1,1, 256,128,1,1,
                                    1,1,1, 1,1,1, 1,1};

    ConvArgs ca;
    ushort_t* cw[25];
    int off = 0, blk = 0;
    for (int i = 1; i <= 25; ++i) {
        int j = i - 1;
        int cnt = in_sizes[i];
        ca.src[j] = d_in[i];
        ca.dstoff[j] = off;
        ca.count[j] = cnt;
        ca.cumblk[j] = blk;
        ca.mode[j] = kMode[j];
        ca.rowdiv[j] = kRowdiv[j];
        cw[j] = conv + off;
        off += cnt;
        blk += (cnt + 2047) / 2048;
    }
    ca.cumblk[25] = blk;

    // --- MEASUREMENT: convert launched TWICE (idempotent pure function).
    // Δ vs round-6 total (277.9) = true marginal cost of convert incl. dispatch.
    for (int rep = 0; rep < 2; ++rep) {
        convert_kernel<<<blk + 32, 256, 0, stream>>>(ca, conv, x, wlens, slens, dmax, flag);
    }
    // 2) word BiGRU (8 seqs/block, 256 blocks -> all CUs)
    word_gru_kernel<<<dim3(128, 2), 512, 0, stream>>>(
        x, cw[0],
        cw[1], cw[2], cw[3], cw[4],
        cw[5], cw[6], cw[7], cw[8],
        wlens, wout);
    // 3) word attention -> sent
    word_attn_kernel<<<1024, 256, 0, stream>>>(wout, cw[17], cw[18], cw[19], dmax, sent);
    // 4) sentence xp -> spT (192 blocks, wide)
    spt_gemm_kernel<<<dim3(16, 12), 256, 0, stream>>>(sent, cw[9], cw[11], sptf,
                                                      cw[13], cw[15], sptb);
    // 5) sentence BiGRU (8 docs/block, 8 blocks)
    sent_gru_kernel<<<dim3(4, 2), 512, 0, stream>>>(
        sptf, sptb, cw[10], cw[14], cw[12], cw[16], slens, sout);
    // 6) sentence attention + FC -> d_out
    sent_attn_fc_kernel<<<32, 256, 0, stream>>>(sout, cw[20], cw[21], cw[22],
                                                cw[23], cw[24], slens, flag, d_out);
    (void)n_in; (void)out_size; (void)ws_size;
}

// Round 11
// 275.997 us; speedup vs baseline: 1.5892x; 1.0453x over previous
//
#include <hip/hip_runtime.h>
#include <hip/hip_bf16.h>

typedef unsigned short ushort_t;
typedef __attribute__((ext_vector_type(4))) float floatx4;
typedef __attribute__((ext_vector_type(8))) short short8;

#define L2E 1.4426950408889634f

__device__ __forceinline__ float bf2f(ushort_t u) {
    union { unsigned int i; float f; } v; v.i = ((unsigned int)u) << 16; return v.f;
}
__device__ __forceinline__ ushort_t f2bf(float f) {
    union { float f; unsigned int i; } v; v.f = f;
    unsigned int i = v.i;
    i += 0x7fffu + ((i >> 16) & 1u);            // RNE
    return (ushort_t)(i >> 16);
}
__device__ __forceinline__ float fexp2(float x) {
#if __has_builtin(__builtin_amdgcn_exp2f)
    return __builtin_amdgcn_exp2f(x);
#else
    return __expf(x * 0.6931471805599453f);
#endif
}
__device__ __forceinline__ float frcp(float x) {
#if __has_builtin(__builtin_amdgcn_rcpf)
    return __builtin_amdgcn_rcpf(x);
#else
    return 1.f / x;
#endif
}
// σ(x) with pre-scaled input a = −log2e·x ; tanh(x) with y = 2·log2e·x.
__device__ __forceinline__ float sig2(float a)  { return frcp(1.f + fexp2(a)); }
__device__ __forceinline__ float tanh2(float y) { return 1.f - 2.f * frcp(1.f + fexp2(y)); }

__device__ __forceinline__ unsigned int packbf(float a, float b) {
    float2 t; t.x = a; t.y = b;
    __hip_bfloat162 h = __float22bfloat162_rn(t);
    union { __hip_bfloat162 h; unsigned int u; } v; v.h = h; return v.u;
}

__device__ __forceinline__ floatx4 MFMA16(short8 a, short8 b, floatx4 c) {
    return __builtin_amdgcn_mfma_f32_16x16x32_bf16(a, b, c, 0, 0, 0);
}

// LDS-only barrier: lgkmcnt(0) only (vmcnt/expcnt maxed) + raw s_barrier.
__device__ __forceinline__ void bar_lds() {
    __builtin_amdgcn_s_waitcnt(0xc07f);
    __builtin_amdgcn_s_barrier();
}

// 8-seq swizzled LDS index: [chunk c(16)][seq m(8)][8 elems]
#define X8(c, m) ((((c) * 8) + ((m) ^ ((c) & 7))) * 8)
#define SP 264

// ---------------------------------------------------------------------------
// K0: canonicalize inputs -> bf16 (folding activation scales into weights),
// PLUS (merged) the lens/dtype work as 32 appended blocks. Mode-1 row test
// uses base+e < 256*rd (exact equiv of (base+e)/rd < 256; gfx950 has no
// integer divide — the old form cost a ~30-op sequence per element).
// ---------------------------------------------------------------------------
struct ConvArgs {
    const void* src[25];
    int dstoff[25];
    int count[25];
    int cumblk[26];
    int mode[25];     // 0 none, 1 GRU (row<256 ? -L2E : 2L2E), 2 all 2L2E
    int rowdiv[25];
};

__global__ __launch_bounds__(256) void convert_kernel(ConvArgs a, ushort_t* __restrict__ dst,
                                                      const int* __restrict__ x,
                                                      int* wlens, int* slens, int* dmax,
                                                      int* flagp) {
    __shared__ int flag_lds;
    int tid = threadIdx.x, b = blockIdx.x;
    if (tid < 64) {
        unsigned int v = ((const unsigned int*)a.src[0])[tid];
        unsigned long long mball = __ballot(((v >> 7) & 0xFFu) > 0x7Bu);
        if (tid == 0) flag_lds = (__popcll(mball) > 8) ? 1 : 0;
    }
    __syncthreads();
    int flagv = flag_lds;
    int cblk = a.cumblk[25];

    if (b >= cblk) {
        int bb = b - cblk;
        if (bb == 0 && tid == 0) *flagp = flagv;
        if (tid < 64) {
            int s = tid;
            int last = 0;
            if (s < 32) {
                const int* tok = x + (bb * 32 + s) * 64;
                for (int t = 0; t < 64; t += 4) {
                    int4 v = *(const int4*)(tok + t);
                    if (v.x) last = t + 1;
                    if (v.y) last = t + 2;
                    if (v.z) last = t + 3;
                    if (v.w) last = t + 4;
                }
                wlens[bb * 32 + s] = last ? last : 1;
            }
            int len = (s < 32) ? (last ? last : 1) : 0;
            int lm = len;
            for (int off = 32; off; off >>= 1) lm = max(lm, __shfl_xor(lm, off));
            unsigned long long mask = __ballot(s < 32 && last > 0);
            if (s == 0) {
                slens[bb] = mask ? (63 - (int)__clzll(mask) + 1) : 1;
                dmax[bb] = lm;
            }
        }
        return;
    }

    int lo = 0, hi = 24;
    while (lo < hi) { int mid = (lo + hi + 1) >> 1; if (a.cumblk[mid] <= b) lo = mid; else hi = mid - 1; }
    int j = lo;
    int base = (b - a.cumblk[j]) * 2048 + tid * 8;
    if (base >= a.count[j]) return;
    ushort_t* out = dst + a.dstoff[j] + base;
    int m = a.mode[j];
    int thr = a.rowdiv[j] << 8;              // 256*rd: (base+e)/rd<256 <=> base+e<thr
    float f[8];
    if (flagv) {
        const float* s = (const float*)a.src[j] + base;
        float4 v0 = *(const float4*)s;
        float4 v1 = *(const float4*)(s + 4);
        f[0] = v0.x; f[1] = v0.y; f[2] = v0.z; f[3] = v0.w;
        f[4] = v1.x; f[5] = v1.y; f[6] = v1.z; f[7] = v1.w;
    } else {
        const ushort_t* s = (const ushort_t*)a.src[j] + base;
        uint4 v = *(const uint4*)s;
        const ushort_t* u = (const ushort_t*)&v;
        #pragma unroll
        for (int e = 0; e < 8; ++e) f[e] = bf2f(u[e]);
    }
    union { ushort_t u[8]; uint4 v; } o;
    #pragma unroll
    for (int e = 0; e < 8; ++e) {
        float sc = 1.f;
        if (m == 2) sc = 2.f * L2E;
        else if (m == 1) sc = (base + e < thr) ? -L2E : 2.f * L2E;
        o.u[e] = f2bf(f[e] * sc);
    }
    *(uint4*)out = o.v;
}

// ---------------------------------------------------------------------------
// Word-level BiGRU v5 (round-1 form — verified local optimum; do not touch):
// 8 seqs/block, grid (128,2) = 256 blocks. 512 thr / 8 waves.
// ---------------------------------------------------------------------------
__global__ __launch_bounds__(512, 2) void word_gru_kernel(
        const int* __restrict__ x, const ushort_t* __restrict__ emb,
        const ushort_t* __restrict__ Wih_f, const ushort_t* __restrict__ Whh_f,
        const ushort_t* __restrict__ bih_f, const ushort_t* __restrict__ bhh_f,
        const ushort_t* __restrict__ Wih_b, const ushort_t* __restrict__ Whh_b,
        const ushort_t* __restrict__ bih_b, const ushort_t* __restrict__ bhh_b,
        const int* __restrict__ lens, ushort_t* __restrict__ out) {
    const int T = 64;
    __shared__ ushort_t h_buf[2][1024];      // [chunk16][seq8][8] swizzled
    __shared__ float bsum_lds[256];
    __shared__ float bihn_lds[128];
    __shared__ float bhhn_lds[128];
    __shared__ int tok_lds[512];             // [t][s(8)]

    int tid = threadIdx.x;
    int d = blockIdx.y;
    int n0 = blockIdx.x * 8;
    const ushort_t* Wih = d ? Wih_b : Wih_f;
    const ushort_t* Whh = d ? Whh_b : Whh_f;
    const ushort_t* bih = d ? bih_b : bih_f;
    const ushort_t* bhh = d ? bhh_b : bhh_f;
    int lane = tid & 63, wave = tid >> 6;
    int l15 = lane & 15, l4 = (lane >> 4) & 3;
    int s8 = l15 & 7;                        // clamped seq index
    bool sv = l15 < 8;                       // this lane's col is valid
    int jt = wave * 16;
    int j0 = jt + l4 * 4;

    {
        int t = tid >> 3, s = tid & 7;
        tok_lds[tid] = x[(n0 + s) * 64 + t];
    }
    if (tid < 256) bsum_lds[tid] = bf2f(bih[tid]) + bf2f(bhh[tid]);
    else if (tid < 384) {
        bihn_lds[tid - 256] = bf2f(bih[tid]);
        bhhn_lds[tid - 256] = bf2f(bhh[tid]);
    }
    if (tid < 256) { uint2 z = {0u, 0u}; *(uint2*)&h_buf[0][tid * 4] = z; }

    short8 wr[4], wz[4], wn[4], ur[4], uz[4], un[4];
    #pragma unroll
    for (int kf = 0; kf < 4; ++kf) {
        int col = kf * 32 + l4 * 8;
        wr[kf] = *(const short8*)(Wih + (size_t)(jt + l15) * 128 + col);
        wz[kf] = *(const short8*)(Wih + (size_t)(128 + jt + l15) * 128 + col);
        wn[kf] = *(const short8*)(Wih + (size_t)(256 + jt + l15) * 128 + col);
        ur[kf] = *(const short8*)(Whh + (size_t)(jt + l15) * 128 + col);
        uz[kf] = *(const short8*)(Whh + (size_t)(128 + jt + l15) * 128 + col);
        un[kf] = *(const short8*)(Whh + (size_t)(256 + jt + l15) * 128 + col);
    }
    __syncthreads();

    floatx4 br  = *(floatx4*)&bsum_lds[j0];
    floatx4 bz  = *(floatx4*)&bsum_lds[128 + j0];
    floatx4 bxn = *(floatx4*)&bihn_lds[j0];
    floatx4 bhn = *(floatx4*)&bhhn_lds[j0];
    int lv = lens[n0 + s8];
    float hreg[4] = {0.f, 0.f, 0.f, 0.f};

    short8 xc[4], xn_[4];
    {
        int t0 = d ? (T - 1) : 0;
        size_t rb = (size_t)tok_lds[t0 * 8 + s8] * 128 + l4 * 8;
        #pragma unroll
        for (int kf = 0; kf < 4; ++kf)
            xc[kf] = *(const short8*)(emb + rb + kf * 32);
    }

    for (int ti = 0; ti < T; ++ti) {
        int t = d ? (T - 1 - ti) : ti;
        bool have_next = (ti + 1) < T;
        if (have_next) {
            int tn = d ? (T - 2 - ti) : (ti + 1);
            size_t rb = (size_t)tok_lds[tn * 8 + s8] * 128 + l4 * 8;
            #pragma unroll
            for (int kf = 0; kf < 4; ++kf)
                xn_[kf] = *(const short8*)(emb + rb + kf * 32);
        }
        short8 hb[4];
        #pragma unroll
        for (int kf = 0; kf < 4; ++kf)
            hb[kf] = *(const short8*)&h_buf[ti & 1][X8(kf * 4 + l4, s8)];
        floatx4 arx = br, azx = bz, axn = bxn;
        floatx4 arh = {0.f, 0.f, 0.f, 0.f}, azh = {0.f, 0.f, 0.f, 0.f}, ahn = bhn;
        #pragma unroll
        for (int kf = 0; kf < 4; ++kf) {
            arx = MFMA16(wr[kf], xc[kf], arx);
            azx = MFMA16(wz[kf], xc[kf], azx);
            axn = MFMA16(wn[kf], xc[kf], axn);
        }
        #pragma unroll
        for (int kf = 0; kf < 4; ++kf) {
            arh = MFMA16(ur[kf], hb[kf], arh);
            azh = MFMA16(uz[kf], hb[kf], azh);
            ahn = MFMA16(un[kf], hb[kf], ahn);
        }
        bool valid = t < lv;
        float hnew[4];
        #pragma unroll
        for (int i = 0; i < 4; ++i) {
            float r  = sig2(arx[i] + arh[i]);
            float z  = sig2(azx[i] + azh[i]);
            float nn = tanh2(axn[i] + r * ahn[i]);
            hnew[i] = valid ? (nn + z * (hreg[i] - nn)) : hreg[i];
            hreg[i] = hnew[i];
        }
        if (sv) {
            uint2 h2, o2;
            h2.x = packbf(hnew[0], hnew[1]);
            h2.y = packbf(hnew[2], hnew[3]);
            o2.x = valid ? h2.x : 0u;
            o2.y = valid ? h2.y : 0u;
            *(uint2*)&h_buf[(ti & 1) ^ 1][X8(j0 >> 3, s8) + (j0 & 7)] = h2;
            *(uint2*)(out + ((size_t)(n0 + s8) * T + t) * 256 + d * 128 + j0) = o2;
        }
        if (have_next) {
            #pragma unroll
            for (int kf = 0; kf < 4; ++kf) xc[kf] = xn_[kf];
        }
        bar_lds();
    }
}

// ---------------------------------------------------------------------------
// Sentence xp GEMM -> transposed layout spT (weights pre-scaled at convert).
// 192 blocks — keep wide; 8-block fusion cost +56 µs (round-5 lesson).
// ---------------------------------------------------------------------------
__global__ __launch_bounds__(256) void spt_gemm_kernel(const ushort_t* __restrict__ A,
                                                       const ushort_t* __restrict__ Bf_,
                                                       const ushort_t* __restrict__ biasf,
                                                       ushort_t* __restrict__ Tf_,
                                                       const ushort_t* __restrict__ Bb_,
                                                       const ushort_t* __restrict__ biasb,
                                                       ushort_t* __restrict__ Tb_) {
    __shared__ ushort_t As[64 * 256];
    __shared__ ushort_t Bs[64 * 256];
    const int K = 256;
    int tid = threadIdx.x;
    int by = blockIdx.y;
    bool sb = by >= 6;
    int n0 = (sb ? by - 6 : by) * 64;
    const ushort_t* B = sb ? Bb_ : Bf_;
    const ushort_t* bias = sb ? biasb : biasf;
    ushort_t* Tp = sb ? Tb_ : Tf_;
    int m0 = blockIdx.x * 64;
    for (int idx = tid; idx < 2048; idx += 256) {
        int m = idx & 63, c = idx >> 6;
        *(uint4*)&As[(c * 64 + m) * 8] = *(const uint4*)(A + (size_t)(m0 + m) * K + c * 8);
    }
    for (int idx = tid; idx < 2048; idx += 256) {
        int n = idx & 63, c = idx >> 6;
        *(uint4*)&Bs[(c * 64 + n) * 8] = *(const uint4*)(B + (size_t)(n0 + n) * K + c * 8);
    }
    __syncthreads();
    int lane = tid & 63, wave = tid >> 6;
    int wm = (wave & 1) * 32, wn = (wave >> 1) * 32;
    int l15 = lane & 15, l4 = lane >> 4;
    floatx4 acc[2][2] = {};
    for (int kf = 0; kf < 8; ++kf) {
        int c = kf * 4 + l4;
        short8 a0 = *(const short8*)&As[(c * 64 + wm + l15) * 8];
        short8 a1 = *(const short8*)&As[(c * 64 + wm + 16 + l15) * 8];
        short8 b0 = *(const short8*)&Bs[(c * 64 + wn + l15) * 8];
        short8 b1 = *(const short8*)&Bs[(c * 64 + wn + 16 + l15) * 8];
        acc[0][0] = MFMA16(a0, b0, acc[0][0]);
        acc[0][1] = MFMA16(a0, b1, acc[0][1]);
        acc[1][0] = MFMA16(a1, b0, acc[1][0]);
        acc[1][1] = MFMA16(a1, b1, acc[1][1]);
    }
    for (int nt = 0; nt < 2; ++nt) {
        int n = n0 + wn + nt * 16 + l15;
        float bv = bf2f(bias[n]);
        int jc = n >> 2, ji = n & 3;
        for (int mt = 0; mt < 2; ++mt) {
            int mbase = m0 + wm + mt * 16 + l4 * 4;
            #pragma unroll
            for (int i = 0; i < 4; ++i) {
                int m = mbase + i;
                int doc = m >> 5, t = m & 31;
                size_t dst = ((size_t)((doc >> 4) * 32 + t) * 96 + jc) * 64
                           + (doc & 15) * 4 + ji;
                Tp[dst] = f2bf(acc[mt][nt][i] + bv);
            }
        }
    }
}

// ---------------------------------------------------------------------------
// Sentence-level BiGRU: 8 docs/block, grid (4,2) = 8 blocks. (round-1 form)
// ---------------------------------------------------------------------------
__global__ __launch_bounds__(512, 2) void sent_gru_kernel(
        const ushort_t* __restrict__ spT_f, const ushort_t* __restrict__ spT_b,
        const ushort_t* __restrict__ Whh_f, const ushort_t* __restrict__ Whh_b,
        const ushort_t* __restrict__ bhh_f, const ushort_t* __restrict__ bhh_b,
        const int* __restrict__ lens, ushort_t* __restrict__ out) {
    const int T = 32;
    __shared__ ushort_t h_buf[2][1024];
    __shared__ float bhh_lds[384];

    int tid = threadIdx.x;
    int d = blockIdx.y;
    int bx = blockIdx.x;
    int n0 = bx * 8;
    const ushort_t* spT = d ? spT_b : spT_f;
    const ushort_t* Whh = d ? Whh_b : Whh_f;
    const ushort_t* bhh = d ? bhh_b : bhh_f;
    int lane = tid & 63, wave = tid >> 6;
    int l15 = lane & 15, l4 = (lane >> 4) & 3;
    int s8 = l15 & 7;
    bool sv = l15 < 8;
    int jt = wave * 16;
    int j0 = jt + l4 * 4;
    int jc = j0 >> 2;

    if (tid < 384) bhh_lds[tid] = bf2f(bhh[tid]);
    if (tid < 256) { uint2 z = {0u, 0u}; *(uint2*)&h_buf[0][tid * 4] = z; }

    short8 ur[4], uz[4], un[4];
    #pragma unroll
    for (int kf = 0; kf < 4; ++kf) {
        int col = kf * 32 + l4 * 8;
        ur[kf] = *(const short8*)(Whh + (size_t)(jt + l15) * 128 + col);
        uz[kf] = *(const short8*)(Whh + (size_t)(128 + jt + l15) * 128 + col);
        un[kf] = *(const short8*)(Whh + (size_t)(256 + jt + l15) * 128 + col);
    }
    __syncthreads();

    floatx4 br  = *(floatx4*)&bhh_lds[j0];
    floatx4 bz  = *(floatx4*)&bhh_lds[128 + j0];
    floatx4 bhn = *(floatx4*)&bhh_lds[256 + j0];
    int lv = lens[n0 + s8];
    float hreg[4] = {0.f, 0.f, 0.f, 0.f};

    // spT group dblk = bx>>1; doc-within-group = (bx&1)*8 + s8
    const ushort_t* sp = spT + (size_t)((bx >> 1) * 32) * 96 * 64
                       + ((bx & 1) * 8 + s8) * 4;
    ushort4 xr_c, xz_c, xn_c, xr_n, xz_n, xn_n;
    {
        int t0 = d ? (T - 1) : 0;
        size_t rb = (size_t)t0 * 96 * 64;
        xr_c = *(const ushort4*)(sp + rb + (size_t)jc * 64);
        xz_c = *(const ushort4*)(sp + rb + (size_t)(32 + jc) * 64);
        xn_c = *(const ushort4*)(sp + rb + (size_t)(64 + jc) * 64);
    }

    for (int ti = 0; ti < T; ++ti) {
        int t = d ? (T - 1 - ti) : ti;
        int cur = ti & 1;
        bool have_next = (ti + 1) < T;
        if (have_next) {
            int tn = d ? (T - 2 - ti) : (ti + 1);
            size_t rb = (size_t)tn * 96 * 64;
            xr_n = *(const ushort4*)(sp + rb + (size_t)jc * 64);
            xz_n = *(const ushort4*)(sp + rb + (size_t)(32 + jc) * 64);
            xn_n = *(const ushort4*)(sp + rb + (size_t)(64 + jc) * 64);
        }
        floatx4 ar = br, az = bz, ahn = bhn;
        #pragma unroll
        for (int kf = 0; kf < 4; ++kf) {
            short8 hb = *(const short8*)&h_buf[cur][X8(kf * 4 + l4, s8)];
            ar  = MFMA16(ur[kf], hb, ar);
            az  = MFMA16(uz[kf], hb, az);
            ahn = MFMA16(un[kf], hb, ahn);
        }
        float xr[4] = {bf2f(xr_c.x), bf2f(xr_c.y), bf2f(xr_c.z), bf2f(xr_c.w)};
        float xz[4] = {bf2f(xz_c.x), bf2f(xz_c.y), bf2f(xz_c.z), bf2f(xz_c.w)};
        float xn[4] = {bf2f(xn_c.x), bf2f(xn_c.y), bf2f(xn_c.z), bf2f(xn_c.w)};
        bool valid = t < lv;
        float hnew[4];
        #pragma unroll
        for (int i = 0; i < 4; ++i) {
            float r  = sig2(xr[i] + ar[i]);
            float z  = sig2(xz[i] + az[i]);
            float nn = tanh2(xn[i] + r * ahn[i]);
            hnew[i] = valid ? (nn + z * (hreg[i] - nn)) : hreg[i];
            hreg[i] = hnew[i];
        }
        if (sv) {
            uint2 h2, o2;
            h2.x = packbf(hnew[0], hnew[1]);
            h2.y = packbf(hnew[2], hnew[3]);
            o2.x = valid ? h2.x : 0u;
            o2.y = valid ? h2.y : 0u;
            *(uint2*)&h_buf[cur ^ 1][X8(j0 >> 3, s8) + (j0 & 7)] = h2;
            *(uint2*)(out + ((size_t)(n0 + s8) * T + t) * 256 + d * 128 + j0) = o2;
        }
        if (have_next) { xr_c = xr_n; xz_c = xz_n; xn_c = xn_n; }
        bar_lds();
    }
}

// ---------------------------------------------------------------------------
// Word attention fused (proj W,b pre-scaled by 2·log2e). 4-acc epilogue.
// ---------------------------------------------------------------------------
__global__ __launch_bounds__(256) void word_attn_kernel(const ushort_t* __restrict__ wout,
                                                        const ushort_t* __restrict__ W,
                                                        const ushort_t* __restrict__ bias,
                                                        const ushort_t* __restrict__ ctx,
                                                        const int* __restrict__ dmax,
                                                        ushort_t* __restrict__ sent) {
    __shared__ ushort_t tile[64 * SP];
    __shared__ float bc[256];
    __shared__ float sc_lds[64];
    __shared__ float p_lds[64];
    int tid = threadIdx.x, g = blockIdx.x;
    for (int idx = tid; idx < 2048; idx += 256) {
        int row = idx >> 5, k0 = (idx & 31) * 8;
        *(uint4*)&tile[row * SP + k0] = *(const uint4*)(wout + ((size_t)g * 64 + row) * 256 + k0);
    }
    if (tid < 128) bc[tid] = bf2f(bias[tid]);
    else bc[tid] = bf2f(ctx[tid - 128]);
    __syncthreads();
    int lane = tid & 63, wave = tid >> 6;
    int l15 = lane & 15, l4 = (lane >> 4) & 3;
    short8 a[8];
    #pragma unroll
    for (int kf = 0; kf < 8; ++kf)
        a[kf] = *(const short8*)&tile[(wave * 16 + l15) * SP + kf * 32 + l4 * 8];
    floatx4 acc[8];
    #pragma unroll
    for (int nt = 0; nt < 8; ++nt) {
        floatx4 c = {0.f, 0.f, 0.f, 0.f};
        #pragma unroll
        for (int kf = 0; kf < 8; ++kf) {
            short8 b = *(const short8*)(W + (size_t)(nt * 16 + l15) * 256 + kf * 32 + l4 * 8);
            c = MFMA16(a[kf], b, c);
        }
        acc[nt] = c;
    }
    float s[4] = {0.f, 0.f, 0.f, 0.f};
    #pragma unroll
    for (int nt = 0; nt < 8; ++nt) {
        float bv = bc[nt * 16 + l15], cv = bc[128 + nt * 16 + l15];
        #pragma unroll
        for (int i = 0; i < 4; ++i)
            s[i] += tanh2(acc[nt][i] + bv) * cv;
    }
    #pragma unroll
    for (int i = 0; i < 4; ++i) {
        s[i] += __shfl_xor(s[i], 1);
        s[i] += __shfl_xor(s[i], 2);
        s[i] += __shfl_xor(s[i], 4);
        s[i] += __shfl_xor(s[i], 8);
    }
    if (l15 == 0) {
        #pragma unroll
        for (int i = 0; i < 4; ++i) sc_lds[wave * 16 + l4 * 4 + i] = s[i];
    }
    __syncthreads();
    if (tid < 64) {
        int ml = dmax[tid & 31];
        for (int off = 32; off; off >>= 1) ml = max(ml, __shfl_xor(ml, off));
        bool v = tid < ml;
        float sc = v ? sc_lds[tid] : -1e30f;
        float mx = sc;
        for (int off = 32; off; off >>= 1) mx = fmaxf(mx, __shfl_xor(mx, off));
        float e = v ? __expf(sc - mx) : 0.f;
        float sum = e;
        for (int off = 32; off; off >>= 1) sum += __shfl_xor(sum, off);
        p_lds[tid] = e * frcp(fmaxf(sum, 1e-30f));
    }
    __syncthreads();
    float a0 = 0.f, a1 = 0.f, a2 = 0.f, a3 = 0.f;
    for (int t = 0; t < 64; t += 4) {
        a0 += p_lds[t]     * bf2f(tile[t * SP + tid]);
        a1 += p_lds[t + 1] * bf2f(tile[(t + 1) * SP + tid]);
        a2 += p_lds[t + 2] * bf2f(tile[(t + 2) * SP + tid]);
        a3 += p_lds[t + 3] * bf2f(tile[(t + 3) * SP + tid]);
    }
    sent[(size_t)g * 256 + tid] = f2bf((a0 + a1) + (a2 + a3));
}

// ---------------------------------------------------------------------------
// Sentence attention + FC fused (proj pre-scaled; FC unscaled).
// ---------------------------------------------------------------------------
__global__ __launch_bounds__(256) void sent_attn_fc_kernel(const ushort_t* __restrict__ sout,
                                                           const ushort_t* __restrict__ W,
                                                           const ushort_t* __restrict__ bias,
                                                           const ushort_t* __restrict__ ctx,
                                                           const ushort_t* __restrict__ fcW,
                                                           const ushort_t* __restrict__ fcb,
                                                           const int* __restrict__ slens,
                                                           const int* __restrict__ flagp,
                                                           void* __restrict__ outp) {
    __shared__ ushort_t tile[32 * SP];
    __shared__ float bc[256];
    __shared__ float sc_lds[32];
    __shared__ float p_lds[32];
    __shared__ float dv[256];
    int tid = threadIdx.x, g = blockIdx.x;
    for (int idx = tid; idx < 1024; idx += 256) {
        int row = idx >> 5, k0 = (idx & 31) * 8;
        *(uint4*)&tile[row * SP + k0] = *(const uint4*)(sout + ((size_t)g * 32 + row) * 256 + k0);
    }
    if (tid < 128) bc[tid] = bf2f(bias[tid]);
    else bc[tid] = bf2f(ctx[tid - 128]);
    __syncthreads();
    int lane = tid & 63, wave = tid >> 6;
    int l15 = lane & 15, l4 = (lane >> 4) & 3;
    if (wave < 2) {
        short8 a[8];
        #pragma unroll
        for (int kf = 0; kf < 8; ++kf)
            a[kf] = *(const short8*)&tile[(wave * 16 + l15) * SP + kf * 32 + l4 * 8];
        floatx4 acc[8];
        #pragma unroll
        for (int nt = 0; nt < 8; ++nt) {
            floatx4 c = {0.f, 0.f, 0.f, 0.f};
            #pragma unroll
            for (int kf = 0; kf < 8; ++kf) {
                short8 b = *(const short8*)(W + (size_t)(nt * 16 + l15) * 256 + kf * 32 + l4 * 8);
                c = MFMA16(a[kf], b, c);
            }
            acc[nt] = c;
        }
        float s[4] = {0.f, 0.f, 0.f, 0.f};
        #pragma unroll
        for (int nt = 0; nt < 8; ++nt) {
            float bv = bc[nt * 16 + l15], cv = bc[128 + nt * 16 + l15];
            #pragma unroll
            for (int i = 0; i < 4; ++i)
                s[i] += tanh2(acc[nt][i] + bv) * cv;
        }
        #pragma unroll
        for (int i = 0; i < 4; ++i) {
            s[i] += __shfl_xor(s[i], 1);
            s[i] += __shfl_xor(s[i], 2);
            s[i] += __shfl_xor(s[i], 4);
            s[i] += __shfl_xor(s[i], 8);
        }
        if (l15 == 0) {
            #pragma unroll
            for (int i = 0; i < 4; ++i) sc_lds[wave * 16 + l4 * 4 + i] = s[i];
        }
    }
    __syncthreads();
    if (tid < 32) {
        int ml = slens[tid];
        for (int off = 16; off; off >>= 1) ml = max(ml, __shfl_xor(ml, off, 32));
        bool v = tid < ml;
        float sc = v ? sc_lds[tid] : -1e30f;
        float mx = sc;
        for (int off = 16; off; off >>= 1) mx = fmaxf(mx, __shfl_xor(mx, off, 32));
        float e = v ? __expf(sc - mx) : 0.f;
        float sum = e;
        for (int off = 16; off; off >>= 1) sum += __shfl_xor(sum, off, 32);
        p_lds[tid] = e * frcp(fmaxf(sum, 1e-30f));
    }
    __syncthreads();
    float acc2 = 0.f;
    for (int t = 0; t < 32; ++t) acc2 += p_lds[t] * bf2f(tile[t * SP + tid]);
    dv[tid] = acc2;
    __syncthreads();
    int c = tid >> 5, q0 = (tid & 31) * 8;
    float partial = 0.f;
    #pragma unroll
    for (int q = 0; q < 8; ++q)
        partial += dv[q0 + q] * bf2f(fcW[(size_t)c * 256 + q0 + q]);
    for (int off = 16; off; off >>= 1) partial += __shfl_xor(partial, off, 32);
    if ((tid & 31) == 0) {
        float v = partial + bf2f(fcb[c]);
        if (*flagp) ((float*)outp)[g * 8 + c] = v;
        else        ((ushort_t*)outp)[g * 8 + c] = f2bf(v);
    }
}

// ---------------------------------------------------------------------------
extern "C" void kernel_launch(void* const* d_in, const int* in_sizes, int n_in,
                              void* d_out, int out_size, void* d_ws, size_t ws_size,
                              hipStream_t stream) {
    const int* x = (const int*)d_in[0];
    char* ws = (char*)d_ws;

    const size_t O_CONV = 0;            // canonical bf16 inputs (~14 MB)
    const size_t O_WOUT = 14680064;     // [65536,256] bf16  33.55 MB
    const size_t O_SENT = 48234496;     // [1024,256] bf16
    const size_t O_SOUT = 48758784;     // [1024,256] bf16
    const size_t O_SPTF = 49283072;     // spT fwd 1.5MB
    const size_t O_SPTB = 50855936;     // spT bwd
    const size_t O_LENS = 52428800;
    const size_t O_SLEN = 52432896;
    const size_t O_DMAX = 52433024;
    const size_t O_FLAG = 52433152;

    ushort_t* conv = (ushort_t*)(ws + O_CONV);
    ushort_t* wout = (ushort_t*)(ws + O_WOUT);
    ushort_t* sent = (ushort_t*)(ws + O_SENT);
    ushort_t* sout = (ushort_t*)(ws + O_SOUT);
    ushort_t* sptf = (ushort_t*)(ws + O_SPTF);
    ushort_t* sptb = (ushort_t*)(ws + O_SPTB);
    int* wlens = (int*)(ws + O_LENS);
    int* slens = (int*)(ws + O_SLEN);
    int* dmax  = (int*)(ws + O_DMAX);
    int* flag  = (int*)(ws + O_FLAG);

    static const int kMode[25]   = {0, 1,1,1,1, 1,1,1,1, 1,1,1,1, 1,1,1,1, 2,2,0, 2,2,0, 0,0};
    static const int kRowdiv[25] = {1, 128,128,1,1, 128,128,1,1, 256,128,1,1, 256,128,1,1,
                                    1,1,1, 1,1,1, 1,1};

    ConvArgs ca;
    ushort_t* cw[25];
    int off = 0, blk = 0;
    for (int i = 1; i <= 25; ++i) {
        int j = i - 1;
        int cnt = in_sizes[i];
        ca.src[j] = d_in[i];
        ca.dstoff[j] = off;
        ca.count[j] = cnt;
        ca.cumblk[j] = blk;
        ca.mode[j] = kMode[j];
        ca.rowdiv[j] = kRowdiv[j];
        cw[j] = conv + off;
        off += cnt;
        blk += (cnt + 2047) / 2048;
    }
    ca.cumblk[25] = blk;

    // 1) canonicalize + lens + dtype flag (merged; lens = 32 extra blocks)
    convert_kernel<<<blk + 32, 256, 0, stream>>>(ca, conv, x, wlens, slens, dmax, flag);
    // 2) word BiGRU (8 seqs/block, 256 blocks -> all CUs)
    word_gru_kernel<<<dim3(128, 2), 512, 0, stream>>>(
        x, cw[0],
        cw[1], cw[2], cw[3], cw[4],
        cw[5], cw[6], cw[7], cw[8],
        wlens, wout);
    // 3) word attention -> sent
    word_attn_kernel<<<1024, 256, 0, stream>>>(wout, cw[17], cw[18], cw[19], dmax, sent);
    // 4) sentence xp -> spT (192 blocks, wide)
    spt_gemm_kernel<<<dim3(16, 12), 256, 0, stream>>>(sent, cw[9], cw[11], sptf,
                                                      cw[13], cw[15], sptb);
    // 5) sentence BiGRU (8 docs/block, 8 blocks)
    sent_gru_kernel<<<dim3(4, 2), 512, 0, stream>>>(
        sptf, sptb, cw[10], cw[14], cw[12], cw[16], slens, sout);
    // 6) sentence attention + FC -> d_out
    sent_attn_fc_kernel<<<32, 256, 0, stream>>>(sout, cw[20], cw[21], cw[22],
                                                cw[23], cw[24], slens, flag, d_out);
    (void)n_in; (void)out_size; (void)ws_size;
}

// Round 12
// 275.507 us; speedup vs baseline: 1.5920x; 1.0018x over previous
//
#include <hip/hip_runtime.h>
#include <hip/hip_bf16.h>

typedef unsigned short ushort_t;
typedef __attribute__((ext_vector_type(4))) float floatx4;
typedef __attribute__((ext_vector_type(8))) short short8;

#define L2E 1.4426950408889634f

__device__ __forceinline__ float bf2f(ushort_t u) {
    union { unsigned int i; float f; } v; v.i = ((unsigned int)u) << 16; return v.f;
}
__device__ __forceinline__ ushort_t f2bf(float f) {
    union { float f; unsigned int i; } v; v.f = f;
    unsigned int i = v.i;
    i += 0x7fffu + ((i >> 16) & 1u);            // RNE
    return (ushort_t)(i >> 16);
}
__device__ __forceinline__ float fexp2(float x) {
#if __has_builtin(__builtin_amdgcn_exp2f)
    return __builtin_amdgcn_exp2f(x);
#else
    return __expf(x * 0.6931471805599453f);
#endif
}
__device__ __forceinline__ float frcp(float x) {
#if __has_builtin(__builtin_amdgcn_rcpf)
    return __builtin_amdgcn_rcpf(x);
#else
    return 1.f / x;
#endif
}
// σ(x) with pre-scaled input a = −log2e·x ; tanh(x) with y = 2·log2e·x.
__device__ __forceinline__ float sig2(float a)  { return frcp(1.f + fexp2(a)); }
__device__ __forceinline__ float tanh2(float y) { return 1.f - 2.f * frcp(1.f + fexp2(y)); }

__device__ __forceinline__ unsigned int packbf(float a, float b) {
    float2 t; t.x = a; t.y = b;
    __hip_bfloat162 h = __float22bfloat162_rn(t);
    union { __hip_bfloat162 h; unsigned int u; } v; v.h = h; return v.u;
}

__device__ __forceinline__ floatx4 MFMA16(short8 a, short8 b, floatx4 c) {
    return __builtin_amdgcn_mfma_f32_16x16x32_bf16(a, b, c, 0, 0, 0);
}

// LDS-only barrier: lgkmcnt(0) only (vmcnt/expcnt maxed) + raw s_barrier.
__device__ __forceinline__ void bar_lds() {
    __builtin_amdgcn_s_waitcnt(0xc07f);
    __builtin_amdgcn_s_barrier();
}

// 8-seq swizzled LDS index: [chunk c(16)][seq m(8)][8 elems]
#define X8(c, m) ((((c) * 8) + ((m) ^ ((c) & 7))) * 8)
#define SP 264

// ---------------------------------------------------------------------------
// K0: canonicalize inputs -> bf16 (folding activation scales into weights),
// PLUS (merged) the lens/dtype work as 32 appended blocks. Mode-1 row test
// uses base+e < 256*rd (exact equiv of (base+e)/rd < 256; gfx950 has no
// integer divide — the old form cost a ~30-op sequence per element).
// ---------------------------------------------------------------------------
struct ConvArgs {
    const void* src[25];
    int dstoff[25];
    int count[25];
    int cumblk[26];
    int mode[25];     // 0 none, 1 GRU (row<256 ? -L2E : 2L2E), 2 all 2L2E
    int rowdiv[25];
};

__global__ __launch_bounds__(256) void convert_kernel(ConvArgs a, ushort_t* __restrict__ dst,
                                                      const int* __restrict__ x,
                                                      int* wlens, int* slens, int* dmax,
                                                      int* flagp) {
    __shared__ int flag_lds;
    int tid = threadIdx.x, b = blockIdx.x;
    if (tid < 64) {
        unsigned int v = ((const unsigned int*)a.src[0])[tid];
        unsigned long long mball = __ballot(((v >> 7) & 0xFFu) > 0x7Bu);
        if (tid == 0) flag_lds = (__popcll(mball) > 8) ? 1 : 0;
    }
    __syncthreads();
    int flagv = flag_lds;
    int cblk = a.cumblk[25];

    if (b >= cblk) {
        int bb = b - cblk;
        if (bb == 0 && tid == 0) *flagp = flagv;
        if (tid < 64) {
            int s = tid;
            int last = 0;
            if (s < 32) {
                const int* tok = x + (bb * 32 + s) * 64;
                for (int t = 0; t < 64; t += 4) {
                    int4 v = *(const int4*)(tok + t);
                    if (v.x) last = t + 1;
                    if (v.y) last = t + 2;
                    if (v.z) last = t + 3;
                    if (v.w) last = t + 4;
                }
                wlens[bb * 32 + s] = last ? last : 1;
            }
            int len = (s < 32) ? (last ? last : 1) : 0;
            int lm = len;
            for (int off = 32; off; off >>= 1) lm = max(lm, __shfl_xor(lm, off));
            unsigned long long mask = __ballot(s < 32 && last > 0);
            if (s == 0) {
                slens[bb] = mask ? (63 - (int)__clzll(mask) + 1) : 1;
                dmax[bb] = lm;
            }
        }
        return;
    }

    int lo = 0, hi = 24;
    while (lo < hi) { int mid = (lo + hi + 1) >> 1; if (a.cumblk[mid] <= b) lo = mid; else hi = mid - 1; }
    int j = lo;
    int base = (b - a.cumblk[j]) * 2048 + tid * 8;
    if (base >= a.count[j]) return;
    ushort_t* out = dst + a.dstoff[j] + base;
    int m = a.mode[j];
    int thr = a.rowdiv[j] << 8;              // 256*rd: (base+e)/rd<256 <=> base+e<thr
    float f[8];
    if (flagv) {
        const float* s = (const float*)a.src[j] + base;
        float4 v0 = *(const float4*)s;
        float4 v1 = *(const float4*)(s + 4);
        f[0] = v0.x; f[1] = v0.y; f[2] = v0.z; f[3] = v0.w;
        f[4] = v1.x; f[5] = v1.y; f[6] = v1.z; f[7] = v1.w;
    } else {
        const ushort_t* s = (const ushort_t*)a.src[j] + base;
        uint4 v = *(const uint4*)s;
        const ushort_t* u = (const ushort_t*)&v;
        #pragma unroll
        for (int e = 0; e < 8; ++e) f[e] = bf2f(u[e]);
    }
    union { ushort_t u[8]; uint4 v; } o;
    #pragma unroll
    for (int e = 0; e < 8; ++e) {
        float sc = 1.f;
        if (m == 2) sc = 2.f * L2E;
        else if (m == 1) sc = (base + e < thr) ? -L2E : 2.f * L2E;
        o.u[e] = f2bf(f[e] * sc);
    }
    *(uint4*)out = o.v;
}

// ---------------------------------------------------------------------------
// Word-level BiGRU v5 (round-1 form — verified local optimum; do not touch):
// 8 seqs/block, grid (128,2) = 256 blocks. 512 thr / 8 waves.
// ---------------------------------------------------------------------------
__global__ __launch_bounds__(512, 2) void word_gru_kernel(
        const int* __restrict__ x, const ushort_t* __restrict__ emb,
        const ushort_t* __restrict__ Wih_f, const ushort_t* __restrict__ Whh_f,
        const ushort_t* __restrict__ bih_f, const ushort_t* __restrict__ bhh_f,
        const ushort_t* __restrict__ Wih_b, const ushort_t* __restrict__ Whh_b,
        const ushort_t* __restrict__ bih_b, const ushort_t* __restrict__ bhh_b,
        const int* __restrict__ lens, ushort_t* __restrict__ out) {
    const int T = 64;
    __shared__ ushort_t h_buf[2][1024];      // [chunk16][seq8][8] swizzled
    __shared__ float bsum_lds[256];
    __shared__ float bihn_lds[128];
    __shared__ float bhhn_lds[128];
    __shared__ int tok_lds[512];             // [t][s(8)]

    int tid = threadIdx.x;
    int d = blockIdx.y;
    int n0 = blockIdx.x * 8;
    const ushort_t* Wih = d ? Wih_b : Wih_f;
    const ushort_t* Whh = d ? Whh_b : Whh_f;
    const ushort_t* bih = d ? bih_b : bih_f;
    const ushort_t* bhh = d ? bhh_b : bhh_f;
    int lane = tid & 63, wave = tid >> 6;
    int l15 = lane & 15, l4 = (lane >> 4) & 3;
    int s8 = l15 & 7;                        // clamped seq index
    bool sv = l15 < 8;                       // this lane's col is valid
    int jt = wave * 16;
    int j0 = jt + l4 * 4;

    {
        int t = tid >> 3, s = tid & 7;
        tok_lds[tid] = x[(n0 + s) * 64 + t];
    }
    if (tid < 256) bsum_lds[tid] = bf2f(bih[tid]) + bf2f(bhh[tid]);
    else if (tid < 384) {
        bihn_lds[tid - 256] = bf2f(bih[tid]);
        bhhn_lds[tid - 256] = bf2f(bhh[tid]);
    }
    if (tid < 256) { uint2 z = {0u, 0u}; *(uint2*)&h_buf[0][tid * 4] = z; }

    short8 wr[4], wz[4], wn[4], ur[4], uz[4], un[4];
    #pragma unroll
    for (int kf = 0; kf < 4; ++kf) {
        int col = kf * 32 + l4 * 8;
        wr[kf] = *(const short8*)(Wih + (size_t)(jt + l15) * 128 + col);
        wz[kf] = *(const short8*)(Wih + (size_t)(128 + jt + l15) * 128 + col);
        wn[kf] = *(const short8*)(Wih + (size_t)(256 + jt + l15) * 128 + col);
        ur[kf] = *(const short8*)(Whh + (size_t)(jt + l15) * 128 + col);
        uz[kf] = *(const short8*)(Whh + (size_t)(128 + jt + l15) * 128 + col);
        un[kf] = *(const short8*)(Whh + (size_t)(256 + jt + l15) * 128 + col);
    }
    __syncthreads();

    floatx4 br  = *(floatx4*)&bsum_lds[j0];
    floatx4 bz  = *(floatx4*)&bsum_lds[128 + j0];
    floatx4 bxn = *(floatx4*)&bihn_lds[j0];
    floatx4 bhn = *(floatx4*)&bhhn_lds[j0];
    int lv = lens[n0 + s8];
    float hreg[4] = {0.f, 0.f, 0.f, 0.f};

    short8 xc[4], xn_[4];
    {
        int t0 = d ? (T - 1) : 0;
        size_t rb = (size_t)tok_lds[t0 * 8 + s8] * 128 + l4 * 8;
        #pragma unroll
        for (int kf = 0; kf < 4; ++kf)
            xc[kf] = *(const short8*)(emb + rb + kf * 32);
    }

    for (int ti = 0; ti < T; ++ti) {
        int t = d ? (T - 1 - ti) : ti;
        bool have_next = (ti + 1) < T;
        if (have_next) {
            int tn = d ? (T - 2 - ti) : (ti + 1);
            size_t rb = (size_t)tok_lds[tn * 8 + s8] * 128 + l4 * 8;
            #pragma unroll
            for (int kf = 0; kf < 4; ++kf)
                xn_[kf] = *(const short8*)(emb + rb + kf * 32);
        }
        short8 hb[4];
        #pragma unroll
        for (int kf = 0; kf < 4; ++kf)
            hb[kf] = *(const short8*)&h_buf[ti & 1][X8(kf * 4 + l4, s8)];
        floatx4 arx = br, azx = bz, axn = bxn;
        floatx4 arh = {0.f, 0.f, 0.f, 0.f}, azh = {0.f, 0.f, 0.f, 0.f}, ahn = bhn;
        #pragma unroll
        for (int kf = 0; kf < 4; ++kf) {
            arx = MFMA16(wr[kf], xc[kf], arx);
            azx = MFMA16(wz[kf], xc[kf], azx);
            axn = MFMA16(wn[kf], xc[kf], axn);
        }
        #pragma unroll
        for (int kf = 0; kf < 4; ++kf) {
            arh = MFMA16(ur[kf], hb[kf], arh);
            azh = MFMA16(uz[kf], hb[kf], azh);
            ahn = MFMA16(un[kf], hb[kf], ahn);
        }
        bool valid = t < lv;
        float hnew[4];
        #pragma unroll
        for (int i = 0; i < 4; ++i) {
            float r  = sig2(arx[i] + arh[i]);
            float z  = sig2(azx[i] + azh[i]);
            float nn = tanh2(axn[i] + r * ahn[i]);
            hnew[i] = valid ? (nn + z * (hreg[i] - nn)) : hreg[i];
            hreg[i] = hnew[i];
        }
        if (sv) {
            uint2 h2, o2;
            h2.x = packbf(hnew[0], hnew[1]);
            h2.y = packbf(hnew[2], hnew[3]);
            o2.x = valid ? h2.x : 0u;
            o2.y = valid ? h2.y : 0u;
            *(uint2*)&h_buf[(ti & 1) ^ 1][X8(j0 >> 3, s8) + (j0 & 7)] = h2;
            *(uint2*)(out + ((size_t)(n0 + s8) * T + t) * 256 + d * 128 + j0) = o2;
        }
        if (have_next) {
            #pragma unroll
            for (int kf = 0; kf < 4; ++kf) xc[kf] = xn_[kf];
        }
        bar_lds();
    }
}

// ---------------------------------------------------------------------------
// Sentence xp GEMM -> transposed layout spT (weights pre-scaled at convert).
// 192 blocks — keep wide; 8-block fusion cost +56 µs (round-5 lesson).
// ---------------------------------------------------------------------------
__global__ __launch_bounds__(256) void spt_gemm_kernel(const ushort_t* __restrict__ A,
                                                       const ushort_t* __restrict__ Bf_,
                                                       const ushort_t* __restrict__ biasf,
                                                       ushort_t* __restrict__ Tf_,
                                                       const ushort_t* __restrict__ Bb_,
                                                       const ushort_t* __restrict__ biasb,
                                                       ushort_t* __restrict__ Tb_) {
    __shared__ ushort_t As[64 * 256];
    __shared__ ushort_t Bs[64 * 256];
    const int K = 256;
    int tid = threadIdx.x;
    int by = blockIdx.y;
    bool sb = by >= 6;
    int n0 = (sb ? by - 6 : by) * 64;
    const ushort_t* B = sb ? Bb_ : Bf_;
    const ushort_t* bias = sb ? biasb : biasf;
    ushort_t* Tp = sb ? Tb_ : Tf_;
    int m0 = blockIdx.x * 64;
    for (int idx = tid; idx < 2048; idx += 256) {
        int m = idx & 63, c = idx >> 6;
        *(uint4*)&As[(c * 64 + m) * 8] = *(const uint4*)(A + (size_t)(m0 + m) * K + c * 8);
    }
    for (int idx = tid; idx < 2048; idx += 256) {
        int n = idx & 63, c = idx >> 6;
        *(uint4*)&Bs[(c * 64 + n) * 8] = *(const uint4*)(B + (size_t)(n0 + n) * K + c * 8);
    }
    __syncthreads();
    int lane = tid & 63, wave = tid >> 6;
    int wm = (wave & 1) * 32, wn = (wave >> 1) * 32;
    int l15 = lane & 15, l4 = lane >> 4;
    floatx4 acc[2][2] = {};
    for (int kf = 0; kf < 8; ++kf) {
        int c = kf * 4 + l4;
        short8 a0 = *(const short8*)&As[(c * 64 + wm + l15) * 8];
        short8 a1 = *(const short8*)&As[(c * 64 + wm + 16 + l15) * 8];
        short8 b0 = *(const short8*)&Bs[(c * 64 + wn + l15) * 8];
        short8 b1 = *(const short8*)&Bs[(c * 64 + wn + 16 + l15) * 8];
        acc[0][0] = MFMA16(a0, b0, acc[0][0]);
        acc[0][1] = MFMA16(a0, b1, acc[0][1]);
        acc[1][0] = MFMA16(a1, b0, acc[1][0]);
        acc[1][1] = MFMA16(a1, b1, acc[1][1]);
    }
    for (int nt = 0; nt < 2; ++nt) {
        int n = n0 + wn + nt * 16 + l15;
        float bv = bf2f(bias[n]);
        int jc = n >> 2, ji = n & 3;
        for (int mt = 0; mt < 2; ++mt) {
            int mbase = m0 + wm + mt * 16 + l4 * 4;
            #pragma unroll
            for (int i = 0; i < 4; ++i) {
                int m = mbase + i;
                int doc = m >> 5, t = m & 31;
                size_t dst = ((size_t)((doc >> 4) * 32 + t) * 96 + jc) * 64
                           + (doc & 15) * 4 + ji;
                Tp[dst] = f2bf(acc[mt][nt][i] + bv);
            }
        }
    }
}

// ---------------------------------------------------------------------------
// Sentence-level BiGRU: 8 docs/block, grid (4,2) = 8 blocks. (round-1 form)
// ---------------------------------------------------------------------------
__global__ __launch_bounds__(512, 2) void sent_gru_kernel(
        const ushort_t* __restrict__ spT_f, const ushort_t* __restrict__ spT_b,
        const ushort_t* __restrict__ Whh_f, const ushort_t* __restrict__ Whh_b,
        const ushort_t* __restrict__ bhh_f, const ushort_t* __restrict__ bhh_b,
        const int* __restrict__ lens, ushort_t* __restrict__ out) {
    const int T = 32;
    __shared__ ushort_t h_buf[2][1024];
    __shared__ float bhh_lds[384];

    int tid = threadIdx.x;
    int d = blockIdx.y;
    int bx = blockIdx.x;
    int n0 = bx * 8;
    const ushort_t* spT = d ? spT_b : spT_f;
    const ushort_t* Whh = d ? Whh_b : Whh_f;
    const ushort_t* bhh = d ? bhh_b : bhh_f;
    int lane = tid & 63, wave = tid >> 6;
    int l15 = lane & 15, l4 = (lane >> 4) & 3;
    int s8 = l15 & 7;
    bool sv = l15 < 8;
    int jt = wave * 16;
    int j0 = jt + l4 * 4;
    int jc = j0 >> 2;

    if (tid < 384) bhh_lds[tid] = bf2f(bhh[tid]);
    if (tid < 256) { uint2 z = {0u, 0u}; *(uint2*)&h_buf[0][tid * 4] = z; }

    short8 ur[4], uz[4], un[4];
    #pragma unroll
    for (int kf = 0; kf < 4; ++kf) {
        int col = kf * 32 + l4 * 8;
        ur[kf] = *(const short8*)(Whh + (size_t)(jt + l15) * 128 + col);
        uz[kf] = *(const short8*)(Whh + (size_t)(128 + jt + l15) * 128 + col);
        un[kf] = *(const short8*)(Whh + (size_t)(256 + jt + l15) * 128 + col);
    }
    __syncthreads();

    floatx4 br  = *(floatx4*)&bhh_lds[j0];
    floatx4 bz  = *(floatx4*)&bhh_lds[128 + j0];
    floatx4 bhn = *(floatx4*)&bhh_lds[256 + j0];
    int lv = lens[n0 + s8];
    float hreg[4] = {0.f, 0.f, 0.f, 0.f};

    // spT group dblk = bx>>1; doc-within-group = (bx&1)*8 + s8
    const ushort_t* sp = spT + (size_t)((bx >> 1) * 32) * 96 * 64
                       + ((bx & 1) * 8 + s8) * 4;
    ushort4 xr_c, xz_c, xn_c, xr_n, xz_n, xn_n;
    {
        int t0 = d ? (T - 1) : 0;
        size_t rb = (size_t)t0 * 96 * 64;
        xr_c = *(const ushort4*)(sp + rb + (size_t)jc * 64);
        xz_c = *(const ushort4*)(sp + rb + (size_t)(32 + jc) * 64);
        xn_c = *(const ushort4*)(sp + rb + (size_t)(64 + jc) * 64);
    }

    for (int ti = 0; ti < T; ++ti) {
        int t = d ? (T - 1 - ti) : ti;
        int cur = ti & 1;
        bool have_next = (ti + 1) < T;
        if (have_next) {
            int tn = d ? (T - 2 - ti) : (ti + 1);
            size_t rb = (size_t)tn * 96 * 64;
            xr_n = *(const ushort4*)(sp + rb + (size_t)jc * 64);
            xz_n = *(const ushort4*)(sp + rb + (size_t)(32 + jc) * 64);
            xn_n = *(const ushort4*)(sp + rb + (size_t)(64 + jc) * 64);
        }
        floatx4 ar = br, az = bz, ahn = bhn;
        #pragma unroll
        for (int kf = 0; kf < 4; ++kf) {
            short8 hb = *(const short8*)&h_buf[cur][X8(kf * 4 + l4, s8)];
            ar  = MFMA16(ur[kf], hb, ar);
            az  = MFMA16(uz[kf], hb, az);
            ahn = MFMA16(un[kf], hb, ahn);
        }
        float xr[4] = {bf2f(xr_c.x), bf2f(xr_c.y), bf2f(xr_c.z), bf2f(xr_c.w)};
        float xz[4] = {bf2f(xz_c.x), bf2f(xz_c.y), bf2f(xz_c.z), bf2f(xz_c.w)};
        float xn[4] = {bf2f(xn_c.x), bf2f(xn_c.y), bf2f(xn_c.z), bf2f(xn_c.w)};
        bool valid = t < lv;
        float hnew[4];
        #pragma unroll
        for (int i = 0; i < 4; ++i) {
            float r  = sig2(xr[i] + ar[i]);
            float z  = sig2(xz[i] + az[i]);
            float nn = tanh2(xn[i] + r * ahn[i]);
            hnew[i] = valid ? (nn + z * (hreg[i] - nn)) : hreg[i];
            hreg[i] = hnew[i];
        }
        if (sv) {
            uint2 h2, o2;
            h2.x = packbf(hnew[0], hnew[1]);
            h2.y = packbf(hnew[2], hnew[3]);
            o2.x = valid ? h2.x : 0u;
            o2.y = valid ? h2.y : 0u;
            *(uint2*)&h_buf[cur ^ 1][X8(j0 >> 3, s8) + (j0 & 7)] = h2;
            *(uint2*)(out + ((size_t)(n0 + s8) * T + t) * 256 + d * 128 + j0) = o2;
        }
        if (have_next) { xr_c = xr_n; xz_c = xz_n; xn_c = xn_n; }
        bar_lds();
    }
}

// ---------------------------------------------------------------------------
// Word attention fused (proj W,b pre-scaled by 2·log2e). 4-acc epilogue.
// ---------------------------------------------------------------------------
__global__ __launch_bounds__(256) void word_attn_kernel(const ushort_t* __restrict__ wout,
                                                        const ushort_t* __restrict__ W,
                                                        const ushort_t* __restrict__ bias,
                                                        const ushort_t* __restrict__ ctx,
                                                        const int* __restrict__ dmax,
                                                        ushort_t* __restrict__ sent) {
    __shared__ ushort_t tile[64 * SP];
    __shared__ float bc[256];
    __shared__ float sc_lds[64];
    __shared__ float p_lds[64];
    int tid = threadIdx.x, g = blockIdx.x;
    for (int idx = tid; idx < 2048; idx += 256) {
        int row = idx >> 5, k0 = (idx & 31) * 8;
        *(uint4*)&tile[row * SP + k0] = *(const uint4*)(wout + ((size_t)g * 64 + row) * 256 + k0);
    }
    if (tid < 128) bc[tid] = bf2f(bias[tid]);
    else bc[tid] = bf2f(ctx[tid - 128]);
    __syncthreads();
    int lane = tid & 63, wave = tid >> 6;
    int l15 = lane & 15, l4 = (lane >> 4) & 3;
    short8 a[8];
    #pragma unroll
    for (int kf = 0; kf < 8; ++kf)
        a[kf] = *(const short8*)&tile[(wave * 16 + l15) * SP + kf * 32 + l4 * 8];
    floatx4 acc[8];
    #pragma unroll
    for (int nt = 0; nt < 8; ++nt) {
        floatx4 c = {0.f, 0.f, 0.f, 0.f};
        #pragma unroll
        for (int kf = 0; kf < 8; ++kf) {
            short8 b = *(const short8*)(W + (size_t)(nt * 16 + l15) * 256 + kf * 32 + l4 * 8);
            c = MFMA16(a[kf], b, c);
        }
        acc[nt] = c;
    }
    float s[4] = {0.f, 0.f, 0.f, 0.f};
    #pragma unroll
    for (int nt = 0; nt < 8; ++nt) {
        float bv = bc[nt * 16 + l15], cv = bc[128 + nt * 16 + l15];
        #pragma unroll
        for (int i = 0; i < 4; ++i)
            s[i] += tanh2(acc[nt][i] + bv) * cv;
    }
    #pragma unroll
    for (int i = 0; i < 4; ++i) {
        s[i] += __shfl_xor(s[i], 1);
        s[i] += __shfl_xor(s[i], 2);
        s[i] += __shfl_xor(s[i], 4);
        s[i] += __shfl_xor(s[i], 8);
    }
    if (l15 == 0) {
        #pragma unroll
        for (int i = 0; i < 4; ++i) sc_lds[wave * 16 + l4 * 4 + i] = s[i];
    }
    __syncthreads();
    if (tid < 64) {
        int ml = dmax[tid & 31];
        for (int off = 32; off; off >>= 1) ml = max(ml, __shfl_xor(ml, off));
        bool v = tid < ml;
        float sc = v ? sc_lds[tid] : -1e30f;
        float mx = sc;
        for (int off = 32; off; off >>= 1) mx = fmaxf(mx, __shfl_xor(mx, off));
        float e = v ? __expf(sc - mx) : 0.f;
        float sum = e;
        for (int off = 32; off; off >>= 1) sum += __shfl_xor(sum, off);
        p_lds[tid] = e * frcp(fmaxf(sum, 1e-30f));
    }
    __syncthreads();
    float a0 = 0.f, a1 = 0.f, a2 = 0.f, a3 = 0.f;
    for (int t = 0; t < 64; t += 4) {
        a0 += p_lds[t]     * bf2f(tile[t * SP + tid]);
        a1 += p_lds[t + 1] * bf2f(tile[(t + 1) * SP + tid]);
        a2 += p_lds[t + 2] * bf2f(tile[(t + 2) * SP + tid]);
        a3 += p_lds[t + 3] * bf2f(tile[(t + 3) * SP + tid]);
    }
    sent[(size_t)g * 256 + tid] = f2bf((a0 + a1) + (a2 + a3));
}

// ---------------------------------------------------------------------------
// Sentence attention + FC fused (proj pre-scaled; FC unscaled).
// ---------------------------------------------------------------------------
__global__ __launch_bounds__(256) void sent_attn_fc_kernel(const ushort_t* __restrict__ sout,
                                                           const ushort_t* __restrict__ W,
                                                           const ushort_t* __restrict__ bias,
                                                           const ushort_t* __restrict__ ctx,
                                                           const ushort_t* __restrict__ fcW,
                                                           const ushort_t* __restrict__ fcb,
                                                           const int* __restrict__ slens,
                                                           const int* __restrict__ flagp,
                                                           void* __restrict__ outp) {
    __shared__ ushort_t tile[32 * SP];
    __shared__ float bc[256];
    __shared__ float sc_lds[32];
    __shared__ float p_lds[32];
    __shared__ float dv[256];
    int tid = threadIdx.x, g = blockIdx.x;
    for (int idx = tid; idx < 1024; idx += 256) {
        int row = idx >> 5, k0 = (idx & 31) * 8;
        *(uint4*)&tile[row * SP + k0] = *(const uint4*)(sout + ((size_t)g * 32 + row) * 256 + k0);
    }
    if (tid < 128) bc[tid] = bf2f(bias[tid]);
    else bc[tid] = bf2f(ctx[tid - 128]);
    __syncthreads();
    int lane = tid & 63, wave = tid >> 6;
    int l15 = lane & 15, l4 = (lane >> 4) & 3;
    if (wave < 2) {
        short8 a[8];
        #pragma unroll
        for (int kf = 0; kf < 8; ++kf)
            a[kf] = *(const short8*)&tile[(wave * 16 + l15) * SP + kf * 32 + l4 * 8];
        floatx4 acc[8];
        #pragma unroll
        for (int nt = 0; nt < 8; ++nt) {
            floatx4 c = {0.f, 0.f, 0.f, 0.f};
            #pragma unroll
            for (int kf = 0; kf < 8; ++kf) {
                short8 b = *(const short8*)(W + (size_t)(nt * 16 + l15) * 256 + kf * 32 + l4 * 8);
                c = MFMA16(a[kf], b, c);
            }
            acc[nt] = c;
        }
        float s[4] = {0.f, 0.f, 0.f, 0.f};
        #pragma unroll
        for (int nt = 0; nt < 8; ++nt) {
            float bv = bc[nt * 16 + l15], cv = bc[128 + nt * 16 + l15];
            #pragma unroll
            for (int i = 0; i < 4; ++i)
                s[i] += tanh2(acc[nt][i] + bv) * cv;
        }
        #pragma unroll
        for (int i = 0; i < 4; ++i) {
            s[i] += __shfl_xor(s[i], 1);
            s[i] += __shfl_xor(s[i], 2);
            s[i] += __shfl_xor(s[i], 4);
            s[i] += __shfl_xor(s[i], 8);
        }
        if (l15 == 0) {
            #pragma unroll
            for (int i = 0; i < 4; ++i) sc_lds[wave * 16 + l4 * 4 + i] = s[i];
        }
    }
    __syncthreads();
    if (tid < 32) {
        int ml = slens[tid];
        for (int off = 16; off; off >>= 1) ml = max(ml, __shfl_xor(ml, off, 32));
        bool v = tid < ml;
        float sc = v ? sc_lds[tid] : -1e30f;
        float mx = sc;
        for (int off = 16; off; off >>= 1) mx = fmaxf(mx, __shfl_xor(mx, off, 32));
        float e = v ? __expf(sc - mx) : 0.f;
        float sum = e;
        for (int off = 16; off; off >>= 1) sum += __shfl_xor(sum, off, 32);
        p_lds[tid] = e * frcp(fmaxf(sum, 1e-30f));
    }
    __syncthreads();
    float acc2 = 0.f;
    for (int t = 0; t < 32; ++t) acc2 += p_lds[t] * bf2f(tile[t * SP + tid]);
    dv[tid] = acc2;
    __syncthreads();
    int c = tid >> 5, q0 = (tid & 31) * 8;
    float partial = 0.f;
    #pragma unroll
    for (int q = 0; q < 8; ++q)
        partial += dv[q0 + q] * bf2f(fcW[(size_t)c * 256 + q0 + q]);
    for (int off = 16; off; off >>= 1) partial += __shfl_xor(partial, off, 32);
    if ((tid & 31) == 0) {
        float v = partial + bf2f(fcb[c]);
        if (*flagp) ((float*)outp)[g * 8 + c] = v;
        else        ((ushort_t*)outp)[g * 8 + c] = f2bf(v);
    }
}

// ---------------------------------------------------------------------------
extern "C" void kernel_launch(void* const* d_in, const int* in_sizes, int n_in,
                              void* d_out, int out_size, void* d_ws, size_t ws_size,
                              hipStream_t stream) {
    const int* x = (const int*)d_in[0];
    char* ws = (char*)d_ws;

    const size_t O_CONV = 0;            // canonical bf16 inputs (~14 MB)
    const size_t O_WOUT = 14680064;     // [65536,256] bf16  33.55 MB
    const size_t O_SENT = 48234496;     // [1024,256] bf16
    const size_t O_SOUT = 48758784;     // [1024,256] bf16
    const size_t O_SPTF = 49283072;     // spT fwd 1.5MB
    const size_t O_SPTB = 50855936;     // spT bwd
    const size_t O_LENS = 52428800;
    const size_t O_SLEN = 52432896;
    const size_t O_DMAX = 52433024;
    const size_t O_FLAG = 52433152;

    ushort_t* conv = (ushort_t*)(ws + O_CONV);
    ushort_t* wout = (ushort_t*)(ws + O_WOUT);
    ushort_t* sent = (ushort_t*)(ws + O_SENT);
    ushort_t* sout = (ushort_t*)(ws + O_SOUT);
    ushort_t* sptf = (ushort_t*)(ws + O_SPTF);
    ushort_t* sptb = (ushort_t*)(ws + O_SPTB);
    int* wlens = (int*)(ws + O_LENS);
    int* slens = (int*)(ws + O_SLEN);
    int* dmax  = (int*)(ws + O_DMAX);
    int* flag  = (int*)(ws + O_FLAG);

    static const int kMode[25]   = {0, 1,1,1,1, 1,1,1,1, 1,1,1,1, 1,1,1,1, 2,2,0, 2,2,0, 0,0};
    static const int kRowdiv[25] = {1, 128,128,1,1, 128,128,1,1, 256,128,1,1, 256,128,1,1,
                                    1,1,1, 1,1,1, 1,1};

    ConvArgs ca;
    ushort_t* cw[25];
    int off = 0, blk = 0;
    for (int i = 1; i <= 25; ++i) {
        int j = i - 1;
        int cnt = in_sizes[i];
        ca.src[j] = d_in[i];
        ca.dstoff[j] = off;
        ca.count[j] = cnt;
        ca.cumblk[j] = blk;
        ca.mode[j] = kMode[j];
        ca.rowdiv[j] = kRowdiv[j];
        cw[j] = conv + off;
        off += cnt;
        blk += (cnt + 2047) / 2048;
    }
    ca.cumblk[25] = blk;

    // 1) canonicalize + lens + dtype flag (merged; lens = 32 extra blocks)
    convert_kernel<<<blk + 32, 256, 0, stream>>>(ca, conv, x, wlens, slens, dmax, flag);
    // 2) word BiGRU (8 seqs/block, 256 blocks -> all CUs)
    word_gru_kernel<<<dim3(128, 2), 512, 0, stream>>>(
        x, cw[0],
        cw[1], cw[2], cw[3], cw[4],
        cw[5], cw[6], cw[7], cw[8],
        wlens, wout);
    // 3) word attention -> sent
    word_attn_kernel<<<1024, 256, 0, stream>>>(wout, cw[17], cw[18], cw[19], dmax, sent);
    // 4) sentence xp -> spT (192 blocks, wide)
    spt_gemm_kernel<<<dim3(16, 12), 256, 0, stream>>>(sent, cw[9], cw[11], sptf,
                                                      cw[13], cw[15], sptb);
    // 5) sentence BiGRU (8 docs/block, 8 blocks)
    sent_gru_kernel<<<dim3(4, 2), 512, 0, stream>>>(
        sptf, sptb, cw[10], cw[14], cw[12], cw[16], slens, sout);
    // 6) sentence attention + FC -> d_out
    sent_attn_fc_kernel<<<32, 256, 0, stream>>>(sout, cw[20], cw[21], cw[22],
                                                cw[23], cw[24], slens, flag, d_out);
    (void)n_in; (void)out_size; (void)ws_size;
}